// Round 5
// baseline (1287.539 us; speedup 1.0000x reference)
//
#include <hip/hip_runtime.h>
#include <hip/hip_bf16.h>

#define NN 50000
#define NE 800000
#define NG 128
#define CAP 64

typedef __attribute__((ext_vector_type(4))) float f32x4;
typedef __attribute__((ext_vector_type(8))) short bf16x8;
typedef __attribute__((ext_vector_type(4))) short short4v;
typedef __attribute__((ext_vector_type(2))) short short2v;

__device__ __forceinline__ float bf2f(unsigned short u) {
    union { unsigned int i; float f; } c; c.i = ((unsigned int)u) << 16; return c.f;
}
__device__ __forceinline__ unsigned short f2bf(float f) {
    __hip_bfloat16 b = __float2bfloat16(f);
    return *reinterpret_cast<unsigned short*>(&b);
}

// --------------------------------------------------------------- zero deg
__global__ __launch_bounds__(256) void zero_deg(int* __restrict__ deg) {
    int i = blockIdx.x * 256 + threadIdx.x;
    if (i < NN) deg[i] = 0;
}

// ------------------------------------------- build padded adjacency lists
__global__ __launch_bounds__(256) void fill_edges(const int* __restrict__ src,
                                                  const int* __restrict__ dst,
                                                  int* __restrict__ deg,
                                                  int* __restrict__ list) {
    int e = blockIdx.x * 256 + threadIdx.x;
    if (e >= NE) return;
    int d = dst[e], s = src[e];
    if ((unsigned)d >= NN || (unsigned)s >= NN) return;   // defensive
    int slot = atomicAdd(&deg[d], 1);
    if (slot < CAP) list[d * CAP + slot] = s;
}

// ------------------------------------------------- layer-0 feature init
// hbuf[node][0..127] = bf16(x); stride 256 shorts
__global__ __launch_bounds__(256) void init0(const float* __restrict__ x,
                                             unsigned short* __restrict__ h) {
    int i = blockIdx.x * 256 + threadIdx.x;     // over NN*32 f32x4 chunks
    if (i >= NN * 32) return;
    int node = i >> 5, c4 = i & 31;
    f32x4 v = reinterpret_cast<const f32x4*>(x)[i];
    short4v b;
#pragma unroll
    for (int c = 0; c < 4; ++c) b[c] = (short)f2bf(v[c]);
    reinterpret_cast<short4v*>(h)[node * 64 + c4] = b;
}

// ---------------------------------------------- gather-based aggregation
// abuf[i] = h[i] + sum_{s in N(i)} h[s]   (bf16 in, f32 acc, bf16 out)
// One wave per node; lane handles V = D/64 features.
template<int D>
__global__ __launch_bounds__(256) void aggregate(const int* __restrict__ deg,
                                                 const int* __restrict__ list,
                                                 const unsigned short* __restrict__ h,
                                                 unsigned short* __restrict__ abuf) {
    constexpr int V = D / 64;                  // 2 or 4
    int node = blockIdx.x * 4 + (threadIdx.x >> 6);
    if (node >= NN) return;
    const int l = threadIdx.x & 63;
    int d = deg[node]; d = d < CAP ? d : CAP;
    const int* li = list + node * CAP;
    const unsigned short* sp = h + (size_t)node * 256 + l * V;
    float acc[V];
    if (V == 4) { short4v t = *reinterpret_cast<const short4v*>(sp);
#pragma unroll
        for (int c = 0; c < 4; ++c) acc[c] = bf2f((unsigned short)t[c]); }
    else        { short2v t = *reinterpret_cast<const short2v*>(sp);
#pragma unroll
        for (int c = 0; c < 2; ++c) acc[c] = bf2f((unsigned short)t[c]); }
    for (int e = 0; e < d; ++e) {
        int s = li[e];
        const unsigned short* hp = h + (size_t)s * 256 + l * V;
        if (V == 4) {
            short4v hv = *reinterpret_cast<const short4v*>(hp);
#pragma unroll
            for (int c = 0; c < 4; ++c) acc[c] += bf2f((unsigned short)hv[c]);
        } else {
            short2v hv = *reinterpret_cast<const short2v*>(hp);
#pragma unroll
            for (int c = 0; c < 2; ++c) acc[c] += bf2f((unsigned short)hv[c]);
        }
    }
    unsigned short* op = abuf + (size_t)node * 256 + l * V;
    if (V == 4) { short4v t;
#pragma unroll
        for (int c = 0; c < 4; ++c) t[c] = (short)f2bf(acc[c]);
        *reinterpret_cast<short4v*>(op) = t; }
    else        { short2v t;
#pragma unroll
        for (int c = 0; c < 2; ++c) t[c] = (short)f2bf(acc[c]);
        *reinterpret_cast<short2v*>(op) = t; }
}

// --------------------------------------------------- node GEMM (bf16 MFMA)
// AC[M,256] bf16, IN-PLACE: C = act(A[:, 0..K) @ W + bias) overwrites AC.
// Block = 4 waves, tile 64 rows x 256 cols. Safe in-place: block reads only
// its own 64 rows; __syncthreads() before epilogue closes cross-wave race.
template<int K, bool RELU>
__global__ __launch_bounds__(256) void node_gemm(unsigned short* AC,
                                                 const unsigned short* __restrict__ WT,
                                                 const float* __restrict__ bias,
                                                 int M) {
    const int lane = threadIdx.x & 63;
    const int wid  = threadIdx.x >> 6;
    const int row0 = blockIdx.x * 64;
    const int col0 = wid * 64;
    const int r16  = lane & 15;
    const int kg   = lane >> 4;          // k-group 0..3

    f32x4 acc[4][4];
#pragma unroll
    for (int m = 0; m < 4; ++m)
#pragma unroll
        for (int n = 0; n < 4; ++n) acc[m][n] = (f32x4)0.0f;

#pragma unroll
    for (int ks = 0; ks < K / 32; ++ks) {
        const int kb = ks * 32 + kg * 8;
        bf16x8 afr[4];
#pragma unroll
        for (int m = 0; m < 4; ++m) {
            int row = row0 + m * 16 + r16;
            row = row < M ? row : M - 1;
            afr[m] = *reinterpret_cast<const bf16x8*>(AC + (size_t)row * 256 + kb);
        }
#pragma unroll
        for (int n = 0; n < 4; ++n) {
            const int col = col0 + n * 16 + r16;
            bf16x8 bfr = *reinterpret_cast<const bf16x8*>(WT + (size_t)col * K + kb);
#pragma unroll
            for (int m = 0; m < 4; ++m)
                acc[m][n] = __builtin_amdgcn_mfma_f32_16x16x32_bf16(afr[m], bfr, acc[m][n], 0, 0, 0);
        }
    }
    __syncthreads();   // all waves done reading A rows before any C write
    // epilogue: D mapping col = lane&15, row = (lane>>4)*4 + j  [m89]
#pragma unroll
    for (int n = 0; n < 4; ++n) {
        const int col = col0 + n * 16 + r16;
        const float bv = bias[col];
#pragma unroll
        for (int m = 0; m < 4; ++m) {
#pragma unroll
            for (int j = 0; j < 4; ++j) {
                int row = row0 + m * 16 + kg * 4 + j;
                if (row < M) {
                    float v = acc[m][n][j] + bv;
                    if (RELU) v = fmaxf(v, 0.0f);
                    AC[(size_t)row * 256 + col] = f2bf(v);
                }
            }
        }
    }
}

// ------------------------------------------------------------- batchnorm
__global__ __launch_bounds__(256) void bn_stats(const unsigned short* __restrict__ h,
                                                float* __restrict__ part, int nRows) {
    const int t = threadIdx.x;
    float s = 0.f, s2 = 0.f;
    for (int r = blockIdx.x; r < nRows; r += gridDim.x) {
        float v = bf2f(h[(size_t)r * 256 + t]);
        s += v;
        s2 = fmaf(v, v, s2);
    }
    part[blockIdx.x * 512 + t] = s;
    part[blockIdx.x * 512 + 256 + t] = s2;
}

__global__ __launch_bounds__(256) void bn_reduce(const float* __restrict__ part,
                                                 const float* __restrict__ gamma,
                                                 const float* __restrict__ beta,
                                                 float* __restrict__ ss, int NB, float invN) {
    const int t = threadIdx.x;
    float s = 0.f, s2 = 0.f;
    for (int b = 0; b < NB; ++b) {
        s += part[b * 512 + t];
        s2 += part[b * 512 + 256 + t];
    }
    float mu  = s * invN;
    float var = fmaf(-mu, mu, s2 * invN);
    float sc  = gamma[t] * rsqrtf(var + 1e-5f);
    ss[t]       = sc;
    ss[256 + t] = fmaf(-sc, mu, beta[t]);
}

// bn + relu: read abuf (h2, bf16), write hbuf (post-BN h, bf16)
__global__ __launch_bounds__(256) void bn_apply(const unsigned short* __restrict__ a,
                                                const float* __restrict__ ss,
                                                unsigned short* __restrict__ h, int n8) {
    int i = blockIdx.x * 256 + threadIdx.x;
    if (i >= n8) return;
    int j = i & 31;                       // 256 feats = 32 bf16x8 groups
    const f32x4* ssv = reinterpret_cast<const f32x4*>(ss);
    f32x4 sc0 = ssv[2 * j],      sc1 = ssv[2 * j + 1];
    f32x4 sh0 = ssv[64 + 2 * j], sh1 = ssv[64 + 2 * j + 1];
    bf16x8 v = reinterpret_cast<const bf16x8*>(a)[i];
    bf16x8 r;
#pragma unroll
    for (int c = 0; c < 4; ++c)
        r[c] = (short)f2bf(fmaxf(fmaf(bf2f((unsigned short)v[c]), sc0[c], sh0[c]), 0.0f));
#pragma unroll
    for (int c = 0; c < 4; ++c)
        r[4 + c] = (short)f2bf(fmaxf(fmaf(bf2f((unsigned short)v[4 + c]), sc1[c], sh1[c]), 0.0f));
    reinterpret_cast<bf16x8*>(h)[i] = r;
}

// ------------------------------------------------------------- mean pool
__global__ __launch_bounds__(256) void pool_mean(const unsigned short* __restrict__ h,
                                                 const int* __restrict__ batch,
                                                 float* __restrict__ pooled, int nRows) {
    const int g = blockIdx.x, t = threadIdx.x;
    int lo = 0, hi = nRows;
    while (lo < hi) { int mid = (lo + hi) >> 1; if (batch[mid] < g) lo = mid + 1; else hi = mid; }
    int start = lo;
    hi = nRows;
    while (lo < hi) { int mid = (lo + hi) >> 1; if (batch[mid] < g + 1) lo = mid + 1; else hi = mid; }
    int end = lo;
    float s = 0.f;
    for (int r = start; r < end; ++r) s += bf2f(h[(size_t)r * 256 + t]);
    pooled[g * 256 + t] = s / (float)max(end - start, 1);
}

// ----------------------------------------------------- small head GEMMs
template<int K1, int K2, int N, int ACT>
__global__ void head_gemm(const float* __restrict__ A1, const float* __restrict__ A2,
                          const float* __restrict__ W, const float* __restrict__ bias,
                          float* __restrict__ out) {
    __shared__ float srow[K1 + K2];
    const int g = blockIdx.x, t = threadIdx.x;
    for (int i = t; i < K1; i += blockDim.x) srow[i] = A1[g * K1 + i];
    if (K2 > 0)
        for (int i = t; i < K2; i += blockDim.x) srow[K1 + i] = A2[g * K2 + i];
    __syncthreads();
    if (t < N) {
        float acc = bias[t];
        for (int k = 0; k < K1 + K2; ++k) acc = fmaf(srow[k], W[k * N + t], acc);
        if (ACT == 1) acc = fmaxf(acc, 0.0f);
        if (ACT == 2) acc = tanhf(acc) * 0.5f + 0.5f;
        out[g * N + t] = acc;
    }
}

// --------------------------------------------- weight transpose to bf16
struct WTParams {
    const float* src[6];
    unsigned short* dst[6];
    int K[6];
};
__global__ void transpose_w(WTParams p) {
    const int w = blockIdx.x;
    const int K = p.K[w];
    const float* s = p.src[w];
    unsigned short* d = p.dst[w];
    const int total = K * 256;
    for (int idx = threadIdx.x; idx < total; idx += blockDim.x) {
        int n = idx / K, k = idx - n * K;
        d[idx] = f2bf(s[k * 256 + n]);
    }
}

// ---------------------------------------------------------------- launch
extern "C" void kernel_launch(void* const* d_in, const int* in_sizes, int n_in,
                              void* d_out, int out_size, void* d_ws, size_t ws_size,
                              hipStream_t stream) {
    const float* x       = (const float*)d_in[0];
    const int*   ei      = (const int*)d_in[1];
    const int*   batch   = (const int*)d_in[2];
    const float* lattice = (const float*)d_in[3];
    const float* w0a = (const float*)d_in[4],  *b0a = (const float*)d_in[5];
    const float* w0b = (const float*)d_in[6],  *b0b = (const float*)d_in[7];
    const float* g0  = (const float*)d_in[8],  *be0 = (const float*)d_in[9];
    const float* w1a = (const float*)d_in[10], *b1a = (const float*)d_in[11];
    const float* w1b = (const float*)d_in[12], *b1b = (const float*)d_in[13];
    const float* g1  = (const float*)d_in[14], *be1 = (const float*)d_in[15];
    const float* w2a = (const float*)d_in[16], *b2a = (const float*)d_in[17];
    const float* w2b = (const float*)d_in[18], *b2b = (const float*)d_in[19];
    const float* g2  = (const float*)d_in[20], *be2 = (const float*)d_in[21];
    const float* lw1 = (const float*)d_in[22], *lb1 = (const float*)d_in[23];
    const float* lw2 = (const float*)d_in[24], *lb2 = (const float*)d_in[25];
    const float* fc1w= (const float*)d_in[26], *fc1b= (const float*)d_in[27];
    const float* fc2w= (const float*)d_in[28], *fc2b= (const float*)d_in[29];

    const int* srcI = ei;
    const int* dstI = ei + NE;

    char* base = (char*)d_ws;
    size_t used = 0;
    auto alloc = [&](size_t bytes) -> char* {
        char* p = base + used;
        used += (bytes + 255) & ~(size_t)255;
        return p;
    };
    unsigned short* hbuf = (unsigned short*)alloc((size_t)NN * 256 * 2); // 25.6 MB
    unsigned short* abuf = (unsigned short*)alloc((size_t)NN * 256 * 2); // 25.6 MB
    int*            list = (int*)alloc((size_t)NN * CAP * 4);            // 12.8 MB
    int*            deg  = (int*)alloc((size_t)NN * 4);                  //  0.2 MB
    unsigned short* w0aT = (unsigned short*)alloc(256 * 128 * 2);
    unsigned short* w0bT = (unsigned short*)alloc(256 * 256 * 2);
    unsigned short* w1aT = (unsigned short*)alloc(256 * 256 * 2);
    unsigned short* w1bT = (unsigned short*)alloc(256 * 256 * 2);
    unsigned short* w2aT = (unsigned short*)alloc(256 * 256 * 2);
    unsigned short* w2bT = (unsigned short*)alloc(256 * 256 * 2);
    float* part   = (float*)alloc(256 * 512 * 4);
    float* ss     = (float*)alloc(512 * 4);
    float* pooled = (float*)alloc(128 * 256 * 4);
    float* latb   = (float*)alloc(128 * 256 * 4);
    float* latb2  = (float*)alloc(128 * 256 * 4);
    float* c1     = (float*)alloc(128 * 256 * 4);

    // Workspace guard: ws_size is call-invariant, so this branch is
    // deterministic (graph-capture safe). If insufficient, skip all work —
    // yields a readable absmax failure instead of a GPU memory fault.
    if (used > ws_size) return;

    // weight transposes (bf16, [N,K])
    WTParams tp;
    tp.src[0] = w0a; tp.dst[0] = w0aT; tp.K[0] = 128;
    tp.src[1] = w0b; tp.dst[1] = w0bT; tp.K[1] = 256;
    tp.src[2] = w1a; tp.dst[2] = w1aT; tp.K[2] = 256;
    tp.src[3] = w1b; tp.dst[3] = w1bT; tp.K[3] = 256;
    tp.src[4] = w2a; tp.dst[4] = w2aT; tp.K[4] = 256;
    tp.src[5] = w2b; tp.dst[5] = w2bT; tp.K[5] = 256;
    transpose_w<<<6, 256, 0, stream>>>(tp);

    // adjacency (built once; reused by all 3 layers)
    zero_deg<<<(NN + 255) / 256, 256, 0, stream>>>(deg);
    fill_edges<<<(NE + 255) / 256, 256, 0, stream>>>(srcI, dstI, deg, list);

    const int gemmBlocks = (NN + 63) / 64;   // 782
    const int aggBlocks  = (NN + 3) / 4;     // 12500
    const int n8         = NN * 32;          // bf16x8 chunks of [NN][256]

    // ---- layer 0 (D_in = 128)
    init0<<<(NN * 32 + 255) / 256, 256, 0, stream>>>(x, hbuf);
    aggregate<128><<<aggBlocks, 256, 0, stream>>>(deg, list, hbuf, abuf);
    node_gemm<128, true ><<<gemmBlocks, 256, 0, stream>>>(abuf, w0aT, b0a, NN);
    node_gemm<256, false><<<gemmBlocks, 256, 0, stream>>>(abuf, w0bT, b0b, NN);
    bn_stats<<<256, 256, 0, stream>>>(abuf, part, NN);
    bn_reduce<<<1, 256, 0, stream>>>(part, g0, be0, ss, 256, 1.0f / NN);
    bn_apply<<<(n8 + 255) / 256, 256, 0, stream>>>(abuf, ss, hbuf, n8);

    // ---- layer 1
    aggregate<256><<<aggBlocks, 256, 0, stream>>>(deg, list, hbuf, abuf);
    node_gemm<256, true ><<<gemmBlocks, 256, 0, stream>>>(abuf, w1aT, b1a, NN);
    node_gemm<256, false><<<gemmBlocks, 256, 0, stream>>>(abuf, w1bT, b1b, NN);
    bn_stats<<<256, 256, 0, stream>>>(abuf, part, NN);
    bn_reduce<<<1, 256, 0, stream>>>(part, g1, be1, ss, 256, 1.0f / NN);
    bn_apply<<<(n8 + 255) / 256, 256, 0, stream>>>(abuf, ss, hbuf, n8);

    // ---- layer 2
    aggregate<256><<<aggBlocks, 256, 0, stream>>>(deg, list, hbuf, abuf);
    node_gemm<256, true ><<<gemmBlocks, 256, 0, stream>>>(abuf, w2aT, b2a, NN);
    node_gemm<256, false><<<gemmBlocks, 256, 0, stream>>>(abuf, w2bT, b2b, NN);
    bn_stats<<<256, 256, 0, stream>>>(abuf, part, NN);
    bn_reduce<<<1, 256, 0, stream>>>(part, g2, be2, ss, 256, 1.0f / NN);
    bn_apply<<<(n8 + 255) / 256, 256, 0, stream>>>(abuf, ss, hbuf, n8);

    // ---- pooling + head
    pool_mean<<<NG, 256, 0, stream>>>(hbuf, batch, pooled, NN);
    head_gemm<9,   0,   256, 1><<<NG, 256, 0, stream>>>(lattice, nullptr, lw1, lb1, latb);
    head_gemm<256, 0,   256, 1><<<NG, 256, 0, stream>>>(latb, nullptr, lw2, lb2, latb2);
    head_gemm<256, 256, 256, 1><<<NG, 256, 0, stream>>>(pooled, latb2, fc1w, fc1b, c1);
    head_gemm<256, 0,   32,  2><<<NG, 64, 0, stream>>>(c1, nullptr, fc2w, fc2b, (float*)d_out);
}

// Round 8
// 1077.268 us; speedup vs baseline: 1.1952x; 1.1952x over previous
//
#include <hip/hip_runtime.h>
#include <hip/hip_bf16.h>

#define NN 50000
#define NE 800000
#define NG 128
#define CAP 64

typedef __attribute__((ext_vector_type(4))) float f32x4;
typedef __attribute__((ext_vector_type(8))) short bf16x8;
typedef __attribute__((ext_vector_type(4))) short short4v;
typedef __attribute__((ext_vector_type(2))) short short2v;

__device__ __forceinline__ float bf2f(unsigned short u) {
    union { unsigned int i; float f; } c; c.i = ((unsigned int)u) << 16; return c.f;
}
__device__ __forceinline__ unsigned short f2bf(float f) {
    __hip_bfloat16 b = __float2bfloat16(f);
    return *reinterpret_cast<unsigned short*>(&b);
}

// --------------------------------------------------------------- zero deg
__global__ __launch_bounds__(256) void zero_deg(int* __restrict__ deg) {
    int i = blockIdx.x * 256 + threadIdx.x;
    if (i < NN) deg[i] = 0;
}

// ------------------------------------------- build padded adjacency lists
__global__ __launch_bounds__(256) void fill_edges(const int* __restrict__ src,
                                                  const int* __restrict__ dst,
                                                  int* __restrict__ deg,
                                                  int* __restrict__ list) {
    int e = blockIdx.x * 256 + threadIdx.x;
    if (e >= NE) return;
    int d = dst[e], s = src[e];
    if ((unsigned)d >= NN || (unsigned)s >= NN) return;   // defensive
    int slot = atomicAdd(&deg[d], 1);
    if (slot < CAP) list[d * CAP + slot] = s;
}

// ------------------------------------------------- layer-0 feature init
// hbuf[node][0..127] = bf16(x); stride 256 shorts
__global__ __launch_bounds__(256) void init0(const float* __restrict__ x,
                                             unsigned short* __restrict__ h) {
    int i = blockIdx.x * 256 + threadIdx.x;     // over NN*32 f32x4 chunks
    if (i >= NN * 32) return;
    int node = i >> 5, c4 = i & 31;
    f32x4 v = reinterpret_cast<const f32x4*>(x)[i];
    short4v b;
#pragma unroll
    for (int c = 0; c < 4; ++c) b[c] = (short)f2bf(v[c]);
    reinterpret_cast<short4v*>(h)[node * 64 + c4] = b;
}

// ---------------------------------------------- gather-based aggregation
// abuf[i] = h[i] + sum_{s in N(i)} h[s]   (bf16 in, f32 acc, bf16 out)
// One wave per node; lane handles V = D/64 features.
template<int D>
__global__ __launch_bounds__(256) void aggregate(const int* __restrict__ deg,
                                                 const int* __restrict__ list,
                                                 const unsigned short* __restrict__ h,
                                                 unsigned short* __restrict__ abuf) {
    constexpr int V = D / 64;                  // 2 or 4
    int node = blockIdx.x * 4 + (threadIdx.x >> 6);
    if (node >= NN) return;
    const int l = threadIdx.x & 63;
    int d = deg[node]; d = d < CAP ? d : CAP;
    const int* li = list + node * CAP;
    const unsigned short* sp = h + (size_t)node * 256 + l * V;
    float acc[V];
    if (V == 4) { short4v t = *reinterpret_cast<const short4v*>(sp);
#pragma unroll
        for (int c = 0; c < 4; ++c) acc[c] = bf2f((unsigned short)t[c]); }
    else        { short2v t = *reinterpret_cast<const short2v*>(sp);
#pragma unroll
        for (int c = 0; c < 2; ++c) acc[c] = bf2f((unsigned short)t[c]); }
    for (int e = 0; e < d; ++e) {
        int s = li[e];
        const unsigned short* hp = h + (size_t)s * 256 + l * V;
        if (V == 4) {
            short4v hv = *reinterpret_cast<const short4v*>(hp);
#pragma unroll
            for (int c = 0; c < 4; ++c) acc[c] += bf2f((unsigned short)hv[c]);
        } else {
            short2v hv = *reinterpret_cast<const short2v*>(hp);
#pragma unroll
            for (int c = 0; c < 2; ++c) acc[c] += bf2f((unsigned short)hv[c]);
        }
    }
    unsigned short* op = abuf + (size_t)node * 256 + l * V;
    if (V == 4) { short4v t;
#pragma unroll
        for (int c = 0; c < 4; ++c) t[c] = (short)f2bf(acc[c]);
        *reinterpret_cast<short4v*>(op) = t; }
    else        { short2v t;
#pragma unroll
        for (int c = 0; c < 2; ++c) t[c] = (short)f2bf(acc[c]);
        *reinterpret_cast<short2v*>(op) = t; }
}

// --------------------------------------------------- node GEMM (bf16 MFMA)
// AC[M,256] bf16, IN-PLACE: C = act(A[:, 0..K) @ W + bias) overwrites AC.
template<int K, bool RELU>
__global__ __launch_bounds__(256) void node_gemm(unsigned short* AC,
                                                 const unsigned short* __restrict__ WT,
                                                 const float* __restrict__ bias,
                                                 int M) {
    const int lane = threadIdx.x & 63;
    const int wid  = threadIdx.x >> 6;
    const int row0 = blockIdx.x * 64;
    const int col0 = wid * 64;
    const int r16  = lane & 15;
    const int kg   = lane >> 4;          // k-group 0..3

    f32x4 acc[4][4];
#pragma unroll
    for (int m = 0; m < 4; ++m)
#pragma unroll
        for (int n = 0; n < 4; ++n) acc[m][n] = (f32x4)0.0f;

#pragma unroll
    for (int ks = 0; ks < K / 32; ++ks) {
        const int kb = ks * 32 + kg * 8;
        bf16x8 afr[4];
#pragma unroll
        for (int m = 0; m < 4; ++m) {
            int row = row0 + m * 16 + r16;
            row = row < M ? row : M - 1;
            afr[m] = *reinterpret_cast<const bf16x8*>(AC + (size_t)row * 256 + kb);
        }
#pragma unroll
        for (int n = 0; n < 4; ++n) {
            const int col = col0 + n * 16 + r16;
            bf16x8 bfr = *reinterpret_cast<const bf16x8*>(WT + (size_t)col * K + kb);
#pragma unroll
            for (int m = 0; m < 4; ++m)
                acc[m][n] = __builtin_amdgcn_mfma_f32_16x16x32_bf16(afr[m], bfr, acc[m][n], 0, 0, 0);
        }
    }
    __syncthreads();   // all waves done reading A rows before any C write
    // epilogue: D mapping col = lane&15, row = (lane>>4)*4 + j  [m89]
#pragma unroll
    for (int n = 0; n < 4; ++n) {
        const int col = col0 + n * 16 + r16;
        const float bv = bias[col];
#pragma unroll
        for (int m = 0; m < 4; ++m) {
#pragma unroll
            for (int j = 0; j < 4; ++j) {
                int row = row0 + m * 16 + kg * 4 + j;
                if (row < M) {
                    float v = acc[m][n][j] + bv;
                    if (RELU) v = fmaxf(v, 0.0f);
                    AC[(size_t)row * 256 + col] = f2bf(v);
                }
            }
        }
    }
}

// ------------------------------------------------------------- batchnorm
// Vectorized: thread (tf = t&31, rg = t>>5); block reads 8 rows x 256 feats
// per iteration via bf16x8; LDS-reduce over the 8 row-groups.
#define BN_ROWS_PER_BLOCK 196   // 256 * 196 >= 50000
__global__ __launch_bounds__(256) void bn_stats(const unsigned short* __restrict__ h,
                                                float* __restrict__ part, int nRows) {
    const int t  = threadIdx.x;
    const int tf = t & 31;       // feature chunk (8 feats)
    const int rg = t >> 5;       // row group 0..7
    const int r0 = blockIdx.x * BN_ROWS_PER_BLOCK;
    const int r1 = min(r0 + BN_ROWS_PER_BLOCK, nRows);
    float s[8], s2[8];
#pragma unroll
    for (int c = 0; c < 8; ++c) { s[c] = 0.f; s2[c] = 0.f; }
    for (int r = r0 + rg; r < r1; r += 8) {
        bf16x8 hv = reinterpret_cast<const bf16x8*>(h + (size_t)r * 256)[tf];
#pragma unroll
        for (int c = 0; c < 8; ++c) {
            float v = bf2f((unsigned short)hv[c]);
            s[c] += v;
            s2[c] = fmaf(v, v, s2[c]);
        }
    }
    __shared__ float redS[8][256];
    __shared__ float redQ[8][256];
#pragma unroll
    for (int c = 0; c < 8; ++c) {
        redS[rg][tf * 8 + c] = s[c];
        redQ[rg][tf * 8 + c] = s2[c];
    }
    __syncthreads();
    float ts = 0.f, tq = 0.f;
#pragma unroll
    for (int g = 0; g < 8; ++g) { ts += redS[g][t]; tq += redQ[g][t]; }
    part[blockIdx.x * 512 + t]       = ts;
    part[blockIdx.x * 512 + 256 + t] = tq;
}

__global__ __launch_bounds__(256) void bn_reduce(const float* __restrict__ part,
                                                 const float* __restrict__ gamma,
                                                 const float* __restrict__ beta,
                                                 float* __restrict__ ss, int NB, float invN) {
    const int t = threadIdx.x;
    float s = 0.f, s2 = 0.f;
    for (int b = 0; b < NB; ++b) {
        s += part[b * 512 + t];
        s2 += part[b * 512 + 256 + t];
    }
    float mu  = s * invN;
    float var = fmaf(-mu, mu, s2 * invN);
    float sc  = gamma[t] * rsqrtf(var + 1e-5f);
    ss[t]       = sc;
    ss[256 + t] = fmaf(-sc, mu, beta[t]);
}

// bn + relu: read abuf (h2, bf16), write hbuf (post-BN h, bf16)
__global__ __launch_bounds__(256) void bn_apply(const unsigned short* __restrict__ a,
                                                const float* __restrict__ ss,
                                                unsigned short* __restrict__ h, int n8) {
    int i = blockIdx.x * 256 + threadIdx.x;
    if (i >= n8) return;
    int j = i & 31;                       // 256 feats = 32 bf16x8 groups
    const f32x4* ssv = reinterpret_cast<const f32x4*>(ss);
    f32x4 sc0 = ssv[2 * j],      sc1 = ssv[2 * j + 1];
    f32x4 sh0 = ssv[64 + 2 * j], sh1 = ssv[64 + 2 * j + 1];
    bf16x8 v = reinterpret_cast<const bf16x8*>(a)[i];
    bf16x8 r;
#pragma unroll
    for (int c = 0; c < 4; ++c)
        r[c] = (short)f2bf(fmaxf(fmaf(bf2f((unsigned short)v[c]), sc0[c], sh0[c]), 0.0f));
#pragma unroll
    for (int c = 0; c < 4; ++c)
        r[4 + c] = (short)f2bf(fmaxf(fmaf(bf2f((unsigned short)v[4 + c]), sc1[c], sh1[c]), 0.0f));
    reinterpret_cast<bf16x8*>(h)[i] = r;
}

// ------------------------------------------------------------- mean pool
// Vectorized like bn_stats: (tf, rg) layout, bf16x8 loads, LDS reduce.
__global__ __launch_bounds__(256) void pool_mean(const unsigned short* __restrict__ h,
                                                 const int* __restrict__ batch,
                                                 float* __restrict__ pooled, int nRows) {
    const int g  = blockIdx.x;
    const int t  = threadIdx.x;
    const int tf = t & 31;
    const int rg = t >> 5;
    int lo = 0, hi = nRows;
    while (lo < hi) { int mid = (lo + hi) >> 1; if (batch[mid] < g) lo = mid + 1; else hi = mid; }
    int start = lo;
    hi = nRows;
    while (lo < hi) { int mid = (lo + hi) >> 1; if (batch[mid] < g + 1) lo = mid + 1; else hi = mid; }
    int end = lo;
    float s[8];
#pragma unroll
    for (int c = 0; c < 8; ++c) s[c] = 0.f;
    for (int r = start + rg; r < end; r += 8) {
        bf16x8 hv = reinterpret_cast<const bf16x8*>(h + (size_t)r * 256)[tf];
#pragma unroll
        for (int c = 0; c < 8; ++c) s[c] += bf2f((unsigned short)hv[c]);
    }
    __shared__ float red[8][256];
#pragma unroll
    for (int c = 0; c < 8; ++c) red[rg][tf * 8 + c] = s[c];
    __syncthreads();
    float ts = 0.f;
#pragma unroll
    for (int q = 0; q < 8; ++q) ts += red[q][t];
    pooled[g * 256 + t] = ts / (float)max(end - start, 1);
}

// ----------------------------------------------------- small head GEMMs
template<int K1, int K2, int N, int ACT>
__global__ void head_gemm(const float* __restrict__ A1, const float* __restrict__ A2,
                          const float* __restrict__ W, const float* __restrict__ bias,
                          float* __restrict__ out) {
    __shared__ float srow[K1 + K2];
    const int g = blockIdx.x, t = threadIdx.x;
    for (int i = t; i < K1; i += blockDim.x) srow[i] = A1[g * K1 + i];
    if (K2 > 0)
        for (int i = t; i < K2; i += blockDim.x) srow[K1 + i] = A2[g * K2 + i];
    __syncthreads();
    if (t < N) {
        float acc = bias[t];
        for (int k = 0; k < K1 + K2; ++k) acc = fmaf(srow[k], W[k * N + t], acc);
        if (ACT == 1) acc = fmaxf(acc, 0.0f);
        if (ACT == 2) acc = tanhf(acc) * 0.5f + 0.5f;
        out[g * N + t] = acc;
    }
}

// --------------------------------------------- weight transpose to bf16
struct WTParams {
    const float* src[6];
    unsigned short* dst[6];
    int K[6];
};
__global__ void transpose_w(WTParams p) {
    const int w = blockIdx.x;
    const int K = p.K[w];
    const float* s = p.src[w];
    unsigned short* d = p.dst[w];
    const int total = K * 256;
    for (int idx = threadIdx.x; idx < total; idx += blockDim.x) {
        int n = idx / K, k = idx - n * K;
        d[idx] = f2bf(s[k * 256 + n]);
    }
}

// ---------------------------------------------------------------- launch
extern "C" void kernel_launch(void* const* d_in, const int* in_sizes, int n_in,
                              void* d_out, int out_size, void* d_ws, size_t ws_size,
                              hipStream_t stream) {
    const float* x       = (const float*)d_in[0];
    const int*   ei      = (const int*)d_in[1];
    const int*   batch   = (const int*)d_in[2];
    const float* lattice = (const float*)d_in[3];
    const float* w0a = (const float*)d_in[4],  *b0a = (const float*)d_in[5];
    const float* w0b = (const float*)d_in[6],  *b0b = (const float*)d_in[7];
    const float* g0  = (const float*)d_in[8],  *be0 = (const float*)d_in[9];
    const float* w1a = (const float*)d_in[10], *b1a = (const float*)d_in[11];
    const float* w1b = (const float*)d_in[12], *b1b = (const float*)d_in[13];
    const float* g1  = (const float*)d_in[14], *be1 = (const float*)d_in[15];
    const float* w2a = (const float*)d_in[16], *b2a = (const float*)d_in[17];
    const float* w2b = (const float*)d_in[18], *b2b = (const float*)d_in[19];
    const float* g2  = (const float*)d_in[20], *be2 = (const float*)d_in[21];
    const float* lw1 = (const float*)d_in[22], *lb1 = (const float*)d_in[23];
    const float* lw2 = (const float*)d_in[24], *lb2 = (const float*)d_in[25];
    const float* fc1w= (const float*)d_in[26], *fc1b= (const float*)d_in[27];
    const float* fc2w= (const float*)d_in[28], *fc2b= (const float*)d_in[29];

    const int* srcI = ei;
    const int* dstI = ei + NE;

    char* base = (char*)d_ws;
    size_t used = 0;
    auto alloc = [&](size_t bytes) -> char* {
        char* p = base + used;
        used += (bytes + 255) & ~(size_t)255;
        return p;
    };
    unsigned short* hbuf = (unsigned short*)alloc((size_t)NN * 256 * 2); // 25.6 MB
    unsigned short* abuf = (unsigned short*)alloc((size_t)NN * 256 * 2); // 25.6 MB
    int*            list = (int*)alloc((size_t)NN * CAP * 4);            // 12.8 MB
    int*            deg  = (int*)alloc((size_t)NN * 4);                  //  0.2 MB
    unsigned short* w0aT = (unsigned short*)alloc(256 * 128 * 2);
    unsigned short* w0bT = (unsigned short*)alloc(256 * 256 * 2);
    unsigned short* w1aT = (unsigned short*)alloc(256 * 256 * 2);
    unsigned short* w1bT = (unsigned short*)alloc(256 * 256 * 2);
    unsigned short* w2aT = (unsigned short*)alloc(256 * 256 * 2);
    unsigned short* w2bT = (unsigned short*)alloc(256 * 256 * 2);
    float* part   = (float*)alloc(256 * 512 * 4);
    float* ss     = (float*)alloc(512 * 4);
    float* pooled = (float*)alloc(128 * 256 * 4);
    float* latb   = (float*)alloc(128 * 256 * 4);
    float* latb2  = (float*)alloc(128 * 256 * 4);
    float* c1     = (float*)alloc(128 * 256 * 4);

    // Workspace guard (deterministic; graph-capture safe).
    if (used > ws_size) return;

    // weight transposes (bf16, [N,K])
    WTParams tp;
    tp.src[0] = w0a; tp.dst[0] = w0aT; tp.K[0] = 128;
    tp.src[1] = w0b; tp.dst[1] = w0bT; tp.K[1] = 256;
    tp.src[2] = w1a; tp.dst[2] = w1aT; tp.K[2] = 256;
    tp.src[3] = w1b; tp.dst[3] = w1bT; tp.K[3] = 256;
    tp.src[4] = w2a; tp.dst[4] = w2aT; tp.K[4] = 256;
    tp.src[5] = w2b; tp.dst[5] = w2bT; tp.K[5] = 256;
    transpose_w<<<6, 256, 0, stream>>>(tp);

    // adjacency (built once; reused by all 3 layers)
    zero_deg<<<(NN + 255) / 256, 256, 0, stream>>>(deg);
    fill_edges<<<(NE + 255) / 256, 256, 0, stream>>>(srcI, dstI, deg, list);

    const int gemmBlocks = (NN + 63) / 64;   // 782
    const int aggBlocks  = (NN + 3) / 4;     // 12500
    const int n8         = NN * 32;          // bf16x8 chunks of [NN][256]

    // ---- layer 0 (D_in = 128)
    init0<<<(NN * 32 + 255) / 256, 256, 0, stream>>>(x, hbuf);
    aggregate<128><<<aggBlocks, 256, 0, stream>>>(deg, list, hbuf, abuf);
    node_gemm<128, true ><<<gemmBlocks, 256, 0, stream>>>(abuf, w0aT, b0a, NN);
    node_gemm<256, false><<<gemmBlocks, 256, 0, stream>>>(abuf, w0bT, b0b, NN);
    bn_stats<<<256, 256, 0, stream>>>(abuf, part, NN);
    bn_reduce<<<1, 256, 0, stream>>>(part, g0, be0, ss, 256, 1.0f / NN);
    bn_apply<<<(n8 + 255) / 256, 256, 0, stream>>>(abuf, ss, hbuf, n8);

    // ---- layer 1
    aggregate<256><<<aggBlocks, 256, 0, stream>>>(deg, list, hbuf, abuf);
    node_gemm<256, true ><<<gemmBlocks, 256, 0, stream>>>(abuf, w1aT, b1a, NN);
    node_gemm<256, false><<<gemmBlocks, 256, 0, stream>>>(abuf, w1bT, b1b, NN);
    bn_stats<<<256, 256, 0, stream>>>(abuf, part, NN);
    bn_reduce<<<1, 256, 0, stream>>>(part, g1, be1, ss, 256, 1.0f / NN);
    bn_apply<<<(n8 + 255) / 256, 256, 0, stream>>>(abuf, ss, hbuf, n8);

    // ---- layer 2
    aggregate<256><<<aggBlocks, 256, 0, stream>>>(deg, list, hbuf, abuf);
    node_gemm<256, true ><<<gemmBlocks, 256, 0, stream>>>(abuf, w2aT, b2a, NN);
    node_gemm<256, false><<<gemmBlocks, 256, 0, stream>>>(abuf, w2bT, b2b, NN);
    bn_stats<<<256, 256, 0, stream>>>(abuf, part, NN);
    bn_reduce<<<1, 256, 0, stream>>>(part, g2, be2, ss, 256, 1.0f / NN);
    bn_apply<<<(n8 + 255) / 256, 256, 0, stream>>>(abuf, ss, hbuf, n8);

    // ---- pooling + head
    pool_mean<<<NG, 256, 0, stream>>>(hbuf, batch, pooled, NN);
    head_gemm<9,   0,   256, 1><<<NG, 256, 0, stream>>>(lattice, nullptr, lw1, lb1, latb);
    head_gemm<256, 0,   256, 1><<<NG, 256, 0, stream>>>(latb, nullptr, lw2, lb2, latb2);
    head_gemm<256, 256, 256, 1><<<NG, 256, 0, stream>>>(pooled, latb2, fc1w, fc1b, c1);
    head_gemm<256, 0,   32,  2><<<NG, 64, 0, stream>>>(c1, nullptr, fc2w, fc2b, (float*)d_out);
}

// Round 10
// 896.230 us; speedup vs baseline: 1.4366x; 1.2020x over previous
//
#include <hip/hip_runtime.h>
#include <hip/hip_bf16.h>

#define NN 50000
#define NE 800000
#define NG 128
#define CAP 64

typedef __attribute__((ext_vector_type(4))) float f32x4;
typedef __attribute__((ext_vector_type(8))) short bf16x8;
typedef __attribute__((ext_vector_type(4))) short short4v;
typedef __attribute__((ext_vector_type(2))) short short2v;

__device__ __forceinline__ float bf2f(unsigned short u) {
    union { unsigned int i; float f; } c; c.i = ((unsigned int)u) << 16; return c.f;
}
__device__ __forceinline__ unsigned short f2bf(float f) {
    __hip_bfloat16 b = __float2bfloat16(f);
    return *reinterpret_cast<unsigned short*>(&b);
}

template<int V> struct VecPick;
template<> struct VecPick<4> { using T = short4v; };
template<> struct VecPick<2> { using T = short2v; };

// --------------------------------------------------------------- zero deg
__global__ __launch_bounds__(256) void zero_deg(int* __restrict__ deg) {
    int i = blockIdx.x * 256 + threadIdx.x;
    if (i < NN) deg[i] = 0;
}

// ------------------------------------------- build padded adjacency lists
__global__ __launch_bounds__(256) void fill_edges(const int* __restrict__ src,
                                                  const int* __restrict__ dst,
                                                  int* __restrict__ deg,
                                                  int* __restrict__ list) {
    int e = blockIdx.x * 256 + threadIdx.x;
    if (e >= NE) return;
    int d = dst[e], s = src[e];
    if ((unsigned)d >= NN || (unsigned)s >= NN) return;   // defensive
    int slot = atomicAdd(&deg[d], 1);
    if (slot < CAP) list[d * CAP + slot] = s;
}

// ------------------------------------------------- layer-0 feature init
// hbuf[node][0..127] = bf16(x); stride 256 shorts
__global__ __launch_bounds__(256) void init0(const float* __restrict__ x,
                                             unsigned short* __restrict__ h) {
    int i = blockIdx.x * 256 + threadIdx.x;     // over NN*32 f32x4 chunks
    if (i >= NN * 32) return;
    int node = i >> 5, c4 = i & 31;
    f32x4 v = reinterpret_cast<const f32x4*>(x)[i];
    short4v b;
#pragma unroll
    for (int c = 0; c < 4; ++c) b[c] = (short)f2bf(v[c]);
    reinterpret_cast<short4v*>(h)[node * 64 + c4] = b;
}

// ---------------------------------------------- gather-based aggregation
// abuf[i] = h[i] + sum_{s in N(i)} h[s]   (bf16 in, f32 acc, bf16 out)
// One wave per node. Edge loop unrolled x4: 4 independent row loads in
// flight per wave (was 1 -> latency-bound at 30% HBM peak, r8 profile).
template<int D>
__global__ __launch_bounds__(256) void aggregate(const int* __restrict__ deg,
                                                 const int* __restrict__ list,
                                                 const unsigned short* __restrict__ h,
                                                 unsigned short* __restrict__ abuf) {
    constexpr int V = D / 64;                  // 2 or 4
    using VT = typename VecPick<V>::T;
    int node = blockIdx.x * 4 + (threadIdx.x >> 6);
    if (node >= NN) return;
    const int l = threadIdx.x & 63;
    int d = deg[node]; d = d < CAP ? d : CAP;
    const int* li = list + node * CAP;
    float acc[V];
    {
        VT t = *reinterpret_cast<const VT*>(h + (size_t)node * 256 + l * V);
#pragma unroll
        for (int c = 0; c < V; ++c) acc[c] = bf2f((unsigned short)t[c]);
    }
    int e = 0;
    for (; e + 4 <= d; e += 4) {
        int s0 = li[e], s1 = li[e + 1], s2 = li[e + 2], s3 = li[e + 3];
        VT h0 = *reinterpret_cast<const VT*>(h + (size_t)s0 * 256 + l * V);
        VT h1 = *reinterpret_cast<const VT*>(h + (size_t)s1 * 256 + l * V);
        VT h2 = *reinterpret_cast<const VT*>(h + (size_t)s2 * 256 + l * V);
        VT h3 = *reinterpret_cast<const VT*>(h + (size_t)s3 * 256 + l * V);
#pragma unroll
        for (int c = 0; c < V; ++c)
            acc[c] += (bf2f((unsigned short)h0[c]) + bf2f((unsigned short)h1[c]))
                    + (bf2f((unsigned short)h2[c]) + bf2f((unsigned short)h3[c]));
    }
    for (; e < d; ++e) {
        int s = li[e];
        VT hv = *reinterpret_cast<const VT*>(h + (size_t)s * 256 + l * V);
#pragma unroll
        for (int c = 0; c < V; ++c) acc[c] += bf2f((unsigned short)hv[c]);
    }
    VT t;
#pragma unroll
    for (int c = 0; c < V; ++c) t[c] = (short)f2bf(acc[c]);
    *reinterpret_cast<VT*>(abuf + (size_t)node * 256 + l * V) = t;
}

// --------------------------------------------------- node GEMM (bf16 MFMA)
// AC[M,256] bf16, IN-PLACE: C = act(A[:, 0..K) @ W + bias) overwrites AC.
// Epilogue stages the 64x256 block tile in LDS (pad 8 shorts/row), then
// writes coalesced bf16x8 (r8 profile: 2B scalar stores -> 2.4x WRITE_SIZE).
// The barrier between LDS-write and store also closes the in-place hazard.
template<int K, bool RELU>
__global__ __launch_bounds__(256) void node_gemm(unsigned short* AC,
                                                 const unsigned short* __restrict__ WT,
                                                 const float* __restrict__ bias,
                                                 int M) {
    const int lane = threadIdx.x & 63;
    const int wid  = threadIdx.x >> 6;
    const int row0 = blockIdx.x * 64;
    const int col0 = wid * 64;
    const int r16  = lane & 15;
    const int kg   = lane >> 4;          // k-group 0..3

    __shared__ unsigned short ctile[64][264];   // pad 8 shorts vs bank alias

    f32x4 acc[4][4];
#pragma unroll
    for (int m = 0; m < 4; ++m)
#pragma unroll
        for (int n = 0; n < 4; ++n) acc[m][n] = (f32x4)0.0f;

#pragma unroll
    for (int ks = 0; ks < K / 32; ++ks) {
        const int kb = ks * 32 + kg * 8;
        bf16x8 afr[4];
#pragma unroll
        for (int m = 0; m < 4; ++m) {
            int row = row0 + m * 16 + r16;
            row = row < M ? row : M - 1;
            afr[m] = *reinterpret_cast<const bf16x8*>(AC + (size_t)row * 256 + kb);
        }
#pragma unroll
        for (int n = 0; n < 4; ++n) {
            const int col = col0 + n * 16 + r16;
            bf16x8 bfr = *reinterpret_cast<const bf16x8*>(WT + (size_t)col * K + kb);
#pragma unroll
            for (int m = 0; m < 4; ++m)
                acc[m][n] = __builtin_amdgcn_mfma_f32_16x16x32_bf16(afr[m], bfr, acc[m][n], 0, 0, 0);
        }
    }
    // epilogue to LDS: D mapping col = lane&15, row = (lane>>4)*4 + j  [m89]
    // wave wid exclusively owns cols col0..col0+63 -> no write race pre-barrier
#pragma unroll
    for (int n = 0; n < 4; ++n) {
        const int col = col0 + n * 16 + r16;
        const float bv = bias[col];
#pragma unroll
        for (int m = 0; m < 4; ++m) {
#pragma unroll
            for (int j = 0; j < 4; ++j) {
                int lrow = m * 16 + kg * 4 + j;
                float v = acc[m][n][j] + bv;
                if (RELU) v = fmaxf(v, 0.0f);
                ctile[lrow][col] = f2bf(v);
            }
        }
    }
    __syncthreads();   // all A-reads + LDS writes done before any global store
    // cooperative coalesced store: 64 rows x 32 chunks of 8 shorts (16B)
    const int t = threadIdx.x;
#pragma unroll
    for (int c = t; c < 64 * 32; c += 256) {
        int lrow = c >> 5, cc = (c & 31) * 8;
        int grow = row0 + lrow;
        if (grow < M) {
            bf16x8 v = *reinterpret_cast<const bf16x8*>(&ctile[lrow][cc]);
            *reinterpret_cast<bf16x8*>(AC + (size_t)grow * 256 + cc) = v;
        }
    }
}

// ------------------------------------------------------------- batchnorm
// Vectorized: thread (tf = t&31, rg = t>>5); block reads 8 rows x 256 feats
// per iteration via bf16x8; LDS-reduce over the 8 row-groups.
#define BN_ROWS_PER_BLOCK 196   // 256 * 196 >= 50000
__global__ __launch_bounds__(256) void bn_stats(const unsigned short* __restrict__ h,
                                                float* __restrict__ part, int nRows) {
    const int t  = threadIdx.x;
    const int tf = t & 31;       // feature chunk (8 feats)
    const int rg = t >> 5;       // row group 0..7
    const int r0 = blockIdx.x * BN_ROWS_PER_BLOCK;
    const int r1 = min(r0 + BN_ROWS_PER_BLOCK, nRows);
    float s[8], s2[8];
#pragma unroll
    for (int c = 0; c < 8; ++c) { s[c] = 0.f; s2[c] = 0.f; }
    for (int r = r0 + rg; r < r1; r += 8) {
        bf16x8 hv = reinterpret_cast<const bf16x8*>(h + (size_t)r * 256)[tf];
#pragma unroll
        for (int c = 0; c < 8; ++c) {
            float v = bf2f((unsigned short)hv[c]);
            s[c] += v;
            s2[c] = fmaf(v, v, s2[c]);
        }
    }
    __shared__ float redS[8][256];
    __shared__ float redQ[8][256];
#pragma unroll
    for (int c = 0; c < 8; ++c) {
        redS[rg][tf * 8 + c] = s[c];
        redQ[rg][tf * 8 + c] = s2[c];
    }
    __syncthreads();
    float ts = 0.f, tq = 0.f;
#pragma unroll
    for (int g = 0; g < 8; ++g) { ts += redS[g][t]; tq += redQ[g][t]; }
    part[blockIdx.x * 512 + t]       = ts;
    part[blockIdx.x * 512 + 256 + t] = tq;
}

__global__ __launch_bounds__(256) void bn_reduce(const float* __restrict__ part,
                                                 const float* __restrict__ gamma,
                                                 const float* __restrict__ beta,
                                                 float* __restrict__ ss, int NB, float invN) {
    const int t = threadIdx.x;
    float s = 0.f, s2 = 0.f;
    for (int b = 0; b < NB; ++b) {
        s += part[b * 512 + t];
        s2 += part[b * 512 + 256 + t];
    }
    float mu  = s * invN;
    float var = fmaf(-mu, mu, s2 * invN);
    float sc  = gamma[t] * rsqrtf(var + 1e-5f);
    ss[t]       = sc;
    ss[256 + t] = fmaf(-sc, mu, beta[t]);
}

// bn + relu: read abuf (h2, bf16), write hbuf (post-BN h, bf16)
__global__ __launch_bounds__(256) void bn_apply(const unsigned short* __restrict__ a,
                                                const float* __restrict__ ss,
                                                unsigned short* __restrict__ h, int n8) {
    int i = blockIdx.x * 256 + threadIdx.x;
    if (i >= n8) return;
    int j = i & 31;                       // 256 feats = 32 bf16x8 groups
    const f32x4* ssv = reinterpret_cast<const f32x4*>(ss);
    f32x4 sc0 = ssv[2 * j],      sc1 = ssv[2 * j + 1];
    f32x4 sh0 = ssv[64 + 2 * j], sh1 = ssv[64 + 2 * j + 1];
    bf16x8 v = reinterpret_cast<const bf16x8*>(a)[i];
    bf16x8 r;
#pragma unroll
    for (int c = 0; c < 4; ++c)
        r[c] = (short)f2bf(fmaxf(fmaf(bf2f((unsigned short)v[c]), sc0[c], sh0[c]), 0.0f));
#pragma unroll
    for (int c = 0; c < 4; ++c)
        r[4 + c] = (short)f2bf(fmaxf(fmaf(bf2f((unsigned short)v[4 + c]), sc1[c], sh1[c]), 0.0f));
    reinterpret_cast<bf16x8*>(h)[i] = r;
}

// ------------------------------------------------------------- mean pool
// Vectorized like bn_stats: (tf, rg) layout, bf16x8 loads, LDS reduce.
__global__ __launch_bounds__(256) void pool_mean(const unsigned short* __restrict__ h,
                                                 const int* __restrict__ batch,
                                                 float* __restrict__ pooled, int nRows) {
    const int g  = blockIdx.x;
    const int t  = threadIdx.x;
    const int tf = t & 31;
    const int rg = t >> 5;
    int lo = 0, hi = nRows;
    while (lo < hi) { int mid = (lo + hi) >> 1; if (batch[mid] < g) lo = mid + 1; else hi = mid; }
    int start = lo;
    hi = nRows;
    while (lo < hi) { int mid = (lo + hi) >> 1; if (batch[mid] < g + 1) lo = mid + 1; else hi = mid; }
    int end = lo;
    float s[8];
#pragma unroll
    for (int c = 0; c < 8; ++c) s[c] = 0.f;
    for (int r = start + rg; r < end; r += 8) {
        bf16x8 hv = reinterpret_cast<const bf16x8*>(h + (size_t)r * 256)[tf];
#pragma unroll
        for (int c = 0; c < 8; ++c) s[c] += bf2f((unsigned short)hv[c]);
    }
    __shared__ float red[8][256];
#pragma unroll
    for (int c = 0; c < 8; ++c) red[rg][tf * 8 + c] = s[c];
    __syncthreads();
    float ts = 0.f;
#pragma unroll
    for (int q = 0; q < 8; ++q) ts += red[q][t];
    pooled[g * 256 + t] = ts / (float)max(end - start, 1);
}

// ----------------------------------------------------- small head GEMMs
template<int K1, int K2, int N, int ACT>
__global__ void head_gemm(const float* __restrict__ A1, const float* __restrict__ A2,
                          const float* __restrict__ W, const float* __restrict__ bias,
                          float* __restrict__ out) {
    __shared__ float srow[K1 + K2];
    const int g = blockIdx.x, t = threadIdx.x;
    for (int i = t; i < K1; i += blockDim.x) srow[i] = A1[g * K1 + i];
    if (K2 > 0)
        for (int i = t; i < K2; i += blockDim.x) srow[K1 + i] = A2[g * K2 + i];
    __syncthreads();
    if (t < N) {
        float acc = bias[t];
        for (int k = 0; k < K1 + K2; ++k) acc = fmaf(srow[k], W[k * N + t], acc);
        if (ACT == 1) acc = fmaxf(acc, 0.0f);
        if (ACT == 2) acc = tanhf(acc) * 0.5f + 0.5f;
        out[g * N + t] = acc;
    }
}

// --------------------------------------------- weight transpose to bf16
struct WTParams {
    const float* src[6];
    unsigned short* dst[6];
    int K[6];
};
__global__ void transpose_w(WTParams p) {
    const int w = blockIdx.x;
    const int K = p.K[w];
    const float* s = p.src[w];
    unsigned short* d = p.dst[w];
    const int total = K * 256;
    for (int idx = threadIdx.x; idx < total; idx += blockDim.x) {
        int n = idx / K, k = idx - n * K;
        d[idx] = f2bf(s[k * 256 + n]);
    }
}

// ---------------------------------------------------------------- launch
extern "C" void kernel_launch(void* const* d_in, const int* in_sizes, int n_in,
                              void* d_out, int out_size, void* d_ws, size_t ws_size,
                              hipStream_t stream) {
    const float* x       = (const float*)d_in[0];
    const int*   ei      = (const int*)d_in[1];
    const int*   batch   = (const int*)d_in[2];
    const float* lattice = (const float*)d_in[3];
    const float* w0a = (const float*)d_in[4],  *b0a = (const float*)d_in[5];
    const float* w0b = (const float*)d_in[6],  *b0b = (const float*)d_in[7];
    const float* g0  = (const float*)d_in[8],  *be0 = (const float*)d_in[9];
    const float* w1a = (const float*)d_in[10], *b1a = (const float*)d_in[11];
    const float* w1b = (const float*)d_in[12], *b1b = (const float*)d_in[13];
    const float* g1  = (const float*)d_in[14], *be1 = (const float*)d_in[15];
    const float* w2a = (const float*)d_in[16], *b2a = (const float*)d_in[17];
    const float* w2b = (const float*)d_in[18], *b2b = (const float*)d_in[19];
    const float* g2  = (const float*)d_in[20], *be2 = (const float*)d_in[21];
    const float* lw1 = (const float*)d_in[22], *lb1 = (const float*)d_in[23];
    const float* lw2 = (const float*)d_in[24], *lb2 = (const float*)d_in[25];
    const float* fc1w= (const float*)d_in[26], *fc1b= (const float*)d_in[27];
    const float* fc2w= (const float*)d_in[28], *fc2b= (const float*)d_in[29];

    const int* srcI = ei;
    const int* dstI = ei + NE;

    char* base = (char*)d_ws;
    size_t used = 0;
    auto alloc = [&](size_t bytes) -> char* {
        char* p = base + used;
        used += (bytes + 255) & ~(size_t)255;
        return p;
    };
    unsigned short* hbuf = (unsigned short*)alloc((size_t)NN * 256 * 2); // 25.6 MB
    unsigned short* abuf = (unsigned short*)alloc((size_t)NN * 256 * 2); // 25.6 MB
    int*            list = (int*)alloc((size_t)NN * CAP * 4);            // 12.8 MB
    int*            deg  = (int*)alloc((size_t)NN * 4);                  //  0.2 MB
    unsigned short* w0aT = (unsigned short*)alloc(256 * 128 * 2);
    unsigned short* w0bT = (unsigned short*)alloc(256 * 256 * 2);
    unsigned short* w1aT = (unsigned short*)alloc(256 * 256 * 2);
    unsigned short* w1bT = (unsigned short*)alloc(256 * 256 * 2);
    unsigned short* w2aT = (unsigned short*)alloc(256 * 256 * 2);
    unsigned short* w2bT = (unsigned short*)alloc(256 * 256 * 2);
    float* part   = (float*)alloc(256 * 512 * 4);
    float* ss     = (float*)alloc(512 * 4);
    float* pooled = (float*)alloc(128 * 256 * 4);
    float* latb   = (float*)alloc(128 * 256 * 4);
    float* latb2  = (float*)alloc(128 * 256 * 4);
    float* c1     = (float*)alloc(128 * 256 * 4);

    // Workspace guard (deterministic; graph-capture safe).
    if (used > ws_size) return;

    // weight transposes (bf16, [N,K])
    WTParams tp;
    tp.src[0] = w0a; tp.dst[0] = w0aT; tp.K[0] = 128;
    tp.src[1] = w0b; tp.dst[1] = w0bT; tp.K[1] = 256;
    tp.src[2] = w1a; tp.dst[2] = w1aT; tp.K[2] = 256;
    tp.src[3] = w1b; tp.dst[3] = w1bT; tp.K[3] = 256;
    tp.src[4] = w2a; tp.dst[4] = w2aT; tp.K[4] = 256;
    tp.src[5] = w2b; tp.dst[5] = w2bT; tp.K[5] = 256;
    transpose_w<<<6, 256, 0, stream>>>(tp);

    // adjacency (built once; reused by all 3 layers)
    zero_deg<<<(NN + 255) / 256, 256, 0, stream>>>(deg);
    fill_edges<<<(NE + 255) / 256, 256, 0, stream>>>(srcI, dstI, deg, list);

    const int gemmBlocks = (NN + 63) / 64;   // 782
    const int aggBlocks  = (NN + 3) / 4;     // 12500
    const int n8         = NN * 32;          // bf16x8 chunks of [NN][256]

    // ---- layer 0 (D_in = 128)
    init0<<<(NN * 32 + 255) / 256, 256, 0, stream>>>(x, hbuf);
    aggregate<128><<<aggBlocks, 256, 0, stream>>>(deg, list, hbuf, abuf);
    node_gemm<128, true ><<<gemmBlocks, 256, 0, stream>>>(abuf, w0aT, b0a, NN);
    node_gemm<256, false><<<gemmBlocks, 256, 0, stream>>>(abuf, w0bT, b0b, NN);
    bn_stats<<<256, 256, 0, stream>>>(abuf, part, NN);
    bn_reduce<<<1, 256, 0, stream>>>(part, g0, be0, ss, 256, 1.0f / NN);
    bn_apply<<<(n8 + 255) / 256, 256, 0, stream>>>(abuf, ss, hbuf, n8);

    // ---- layer 1
    aggregate<256><<<aggBlocks, 256, 0, stream>>>(deg, list, hbuf, abuf);
    node_gemm<256, true ><<<gemmBlocks, 256, 0, stream>>>(abuf, w1aT, b1a, NN);
    node_gemm<256, false><<<gemmBlocks, 256, 0, stream>>>(abuf, w1bT, b1b, NN);
    bn_stats<<<256, 256, 0, stream>>>(abuf, part, NN);
    bn_reduce<<<1, 256, 0, stream>>>(part, g1, be1, ss, 256, 1.0f / NN);
    bn_apply<<<(n8 + 255) / 256, 256, 0, stream>>>(abuf, ss, hbuf, n8);

    // ---- layer 2
    aggregate<256><<<aggBlocks, 256, 0, stream>>>(deg, list, hbuf, abuf);
    node_gemm<256, true ><<<gemmBlocks, 256, 0, stream>>>(abuf, w2aT, b2a, NN);
    node_gemm<256, false><<<gemmBlocks, 256, 0, stream>>>(abuf, w2bT, b2b, NN);
    bn_stats<<<256, 256, 0, stream>>>(abuf, part, NN);
    bn_reduce<<<1, 256, 0, stream>>>(part, g2, be2, ss, 256, 1.0f / NN);
    bn_apply<<<(n8 + 255) / 256, 256, 0, stream>>>(abuf, ss, hbuf, n8);

    // ---- pooling + head
    pool_mean<<<NG, 256, 0, stream>>>(hbuf, batch, pooled, NN);
    head_gemm<9,   0,   256, 1><<<NG, 256, 0, stream>>>(lattice, nullptr, lw1, lb1, latb);
    head_gemm<256, 0,   256, 1><<<NG, 256, 0, stream>>>(latb, nullptr, lw2, lb2, latb2);
    head_gemm<256, 256, 256, 1><<<NG, 256, 0, stream>>>(pooled, latb2, fc1w, fc1b, c1);
    head_gemm<256, 0,   32,  2><<<NG, 64, 0, stream>>>(c1, nullptr, fc2w, fc2b, (float*)d_out);
}

// Round 13
// 698.907 us; speedup vs baseline: 1.8422x; 1.2823x over previous
//
#include <hip/hip_runtime.h>
#include <hip/hip_bf16.h>

#define NN 50000
#define NE 800000
#define NG 128
#define CAP 64

typedef __attribute__((ext_vector_type(4))) float f32x4;
typedef __attribute__((ext_vector_type(8))) short bf16x8;
typedef __attribute__((ext_vector_type(4))) short short4v;
typedef __attribute__((ext_vector_type(2))) short short2v;

__device__ __forceinline__ float bf2f(unsigned short u) {
    union { unsigned int i; float f; } c; c.i = ((unsigned int)u) << 16; return c.f;
}
__device__ __forceinline__ unsigned short f2bf(float f) {
    __hip_bfloat16 b = __float2bfloat16(f);
    return *reinterpret_cast<unsigned short*>(&b);
}

template<int V> struct VecPick;
template<> struct VecPick<4> { using T = short4v; };
template<> struct VecPick<2> { using T = short2v; };

// --------------------------------------------------------------- zero deg
__global__ __launch_bounds__(256) void zero_deg(int* __restrict__ deg) {
    int i = blockIdx.x * 256 + threadIdx.x;
    if (i < NN) deg[i] = 0;
}

// ------------------------------------------- build padded adjacency lists
__global__ __launch_bounds__(256) void fill_edges(const int* __restrict__ src,
                                                  const int* __restrict__ dst,
                                                  int* __restrict__ deg,
                                                  int* __restrict__ list) {
    int e = blockIdx.x * 256 + threadIdx.x;
    if (e >= NE) return;
    int d = dst[e], s = src[e];
    if ((unsigned)d >= NN || (unsigned)s >= NN) return;   // defensive
    int slot = atomicAdd(&deg[d], 1);
    if (slot < CAP) list[d * CAP + slot] = s;
}

// ------------------------------------------------- layer-0 feature init
// hbuf[node][0..127] = bf16(x); stride 256 shorts
__global__ __launch_bounds__(256) void init0(const float* __restrict__ x,
                                             unsigned short* __restrict__ h) {
    int i = blockIdx.x * 256 + threadIdx.x;     // over NN*32 f32x4 chunks
    if (i >= NN * 32) return;
    int node = i >> 5, c4 = i & 31;
    f32x4 v = reinterpret_cast<const f32x4*>(x)[i];
    short4v b;
#pragma unroll
    for (int c = 0; c < 4; ++c) b[c] = (short)f2bf(v[c]);
    reinterpret_cast<short4v*>(h)[node * 64 + c4] = b;
}

// ---------------------------------------------- gather-based aggregation
// abuf[i] = h[i] + sum_{s in N(i)} h[s]   (bf16 in, f32 acc, bf16 out)
// One wave per node. Edge loop unrolled x4: 4 independent row loads in
// flight per wave (was 1 -> latency-bound at 30% HBM peak, r8 profile).
template<int D>
__global__ __launch_bounds__(256) void aggregate(const int* __restrict__ deg,
                                                 const int* __restrict__ list,
                                                 const unsigned short* __restrict__ h,
                                                 unsigned short* __restrict__ abuf) {
    constexpr int V = D / 64;                  // 2 or 4
    using VT = typename VecPick<V>::T;
    int node = blockIdx.x * 4 + (threadIdx.x >> 6);
    if (node >= NN) return;
    const int l = threadIdx.x & 63;
    int d = deg[node]; d = d < CAP ? d : CAP;
    const int* li = list + node * CAP;
    float acc[V];
    {
        VT t = *reinterpret_cast<const VT*>(h + (size_t)node * 256 + l * V);
#pragma unroll
        for (int c = 0; c < V; ++c) acc[c] = bf2f((unsigned short)t[c]);
    }
    int e = 0;
    for (; e + 4 <= d; e += 4) {
        int s0 = li[e], s1 = li[e + 1], s2 = li[e + 2], s3 = li[e + 3];
        VT h0 = *reinterpret_cast<const VT*>(h + (size_t)s0 * 256 + l * V);
        VT h1 = *reinterpret_cast<const VT*>(h + (size_t)s1 * 256 + l * V);
        VT h2 = *reinterpret_cast<const VT*>(h + (size_t)s2 * 256 + l * V);
        VT h3 = *reinterpret_cast<const VT*>(h + (size_t)s3 * 256 + l * V);
#pragma unroll
        for (int c = 0; c < V; ++c)
            acc[c] += (bf2f((unsigned short)h0[c]) + bf2f((unsigned short)h1[c]))
                    + (bf2f((unsigned short)h2[c]) + bf2f((unsigned short)h3[c]));
    }
    for (; e < d; ++e) {
        int s = li[e];
        VT hv = *reinterpret_cast<const VT*>(h + (size_t)s * 256 + l * V);
#pragma unroll
        for (int c = 0; c < V; ++c) acc[c] += bf2f((unsigned short)hv[c]);
    }
    VT t;
#pragma unroll
    for (int c = 0; c < V; ++c) t[c] = (short)f2bf(acc[c]);
    *reinterpret_cast<VT*>(abuf + (size_t)node * 256 + l * V) = t;
}

// --------------------------------------------------- node GEMM (bf16 MFMA)
// AC[M,256] bf16, IN-PLACE: C = act(A[:, 0..K) @ W + bias) overwrites AC.
// Epilogue stages the 64x256 block tile in LDS (pad 8 shorts/row), then
// writes coalesced bf16x8 (r8 profile: 2B scalar stores -> 2.4x WRITE_SIZE).
// The barrier between LDS-write and store also closes the in-place hazard.
template<int K, bool RELU>
__global__ __launch_bounds__(256) void node_gemm(unsigned short* AC,
                                                 const unsigned short* __restrict__ WT,
                                                 const float* __restrict__ bias,
                                                 int M) {
    const int lane = threadIdx.x & 63;
    const int wid  = threadIdx.x >> 6;
    const int row0 = blockIdx.x * 64;
    const int col0 = wid * 64;
    const int r16  = lane & 15;
    const int kg   = lane >> 4;          // k-group 0..3

    __shared__ unsigned short ctile[64][264];   // pad 8 shorts vs bank alias

    f32x4 acc[4][4];
#pragma unroll
    for (int m = 0; m < 4; ++m)
#pragma unroll
        for (int n = 0; n < 4; ++n) acc[m][n] = (f32x4)0.0f;

#pragma unroll
    for (int ks = 0; ks < K / 32; ++ks) {
        const int kb = ks * 32 + kg * 8;
        bf16x8 afr[4];
#pragma unroll
        for (int m = 0; m < 4; ++m) {
            int row = row0 + m * 16 + r16;
            row = row < M ? row : M - 1;
            afr[m] = *reinterpret_cast<const bf16x8*>(AC + (size_t)row * 256 + kb);
        }
#pragma unroll
        for (int n = 0; n < 4; ++n) {
            const int col = col0 + n * 16 + r16;
            bf16x8 bfr = *reinterpret_cast<const bf16x8*>(WT + (size_t)col * K + kb);
#pragma unroll
            for (int m = 0; m < 4; ++m)
                acc[m][n] = __builtin_amdgcn_mfma_f32_16x16x32_bf16(afr[m], bfr, acc[m][n], 0, 0, 0);
        }
    }
    // epilogue to LDS: D mapping col = lane&15, row = (lane>>4)*4 + j  [m89]
    // wave wid exclusively owns cols col0..col0+63 -> no write race pre-barrier
#pragma unroll
    for (int n = 0; n < 4; ++n) {
        const int col = col0 + n * 16 + r16;
        const float bv = bias[col];
#pragma unroll
        for (int m = 0; m < 4; ++m) {
#pragma unroll
            for (int j = 0; j < 4; ++j) {
                int lrow = m * 16 + kg * 4 + j;
                float v = acc[m][n][j] + bv;
                if (RELU) v = fmaxf(v, 0.0f);
                ctile[lrow][col] = f2bf(v);
            }
        }
    }
    __syncthreads();   // all A-reads + LDS writes done before any global store
    // cooperative coalesced store: 64 rows x 32 chunks of 8 shorts (16B)
    const int t = threadIdx.x;
#pragma unroll
    for (int c = t; c < 64 * 32; c += 256) {
        int lrow = c >> 5, cc = (c & 31) * 8;
        int grow = row0 + lrow;
        if (grow < M) {
            bf16x8 v = *reinterpret_cast<const bf16x8*>(&ctile[lrow][cc]);
            *reinterpret_cast<bf16x8*>(AC + (size_t)grow * 256 + cc) = v;
        }
    }
}

// ------------------------------------------------------------- batchnorm
// Vectorized: thread (tf = t&31, rg = t>>5); block reads 8 rows x 256 feats
// per iteration via bf16x8; LDS-reduce over the 8 row-groups.
#define BN_ROWS_PER_BLOCK 196   // 256 * 196 >= 50000
__global__ __launch_bounds__(256) void bn_stats(const unsigned short* __restrict__ h,
                                                float* __restrict__ part, int nRows) {
    const int t  = threadIdx.x;
    const int tf = t & 31;       // feature chunk (8 feats)
    const int rg = t >> 5;       // row group 0..7
    const int r0 = blockIdx.x * BN_ROWS_PER_BLOCK;
    const int r1 = min(r0 + BN_ROWS_PER_BLOCK, nRows);
    float s[8], s2[8];
#pragma unroll
    for (int c = 0; c < 8; ++c) { s[c] = 0.f; s2[c] = 0.f; }
    for (int r = r0 + rg; r < r1; r += 8) {
        bf16x8 hv = reinterpret_cast<const bf16x8*>(h + (size_t)r * 256)[tf];
#pragma unroll
        for (int c = 0; c < 8; ++c) {
            float v = bf2f((unsigned short)hv[c]);
            s[c] += v;
            s2[c] = fmaf(v, v, s2[c]);
        }
    }
    __shared__ float redS[8][256];
    __shared__ float redQ[8][256];
#pragma unroll
    for (int c = 0; c < 8; ++c) {
        redS[rg][tf * 8 + c] = s[c];
        redQ[rg][tf * 8 + c] = s2[c];
    }
    __syncthreads();
    float ts = 0.f, tq = 0.f;
#pragma unroll
    for (int g = 0; g < 8; ++g) { ts += redS[g][t]; tq += redQ[g][t]; }
    part[blockIdx.x * 512 + t]       = ts;
    part[blockIdx.x * 512 + 256 + t] = tq;
}

// Parallel reduce: one block per FEATURE column f (256 blocks).
// r10 profile: serial 1-block version was 70us at 0.04% occupancy --
// 256-iter latency chain on one CU. Now: thread t loads partial t (all 256
// partials in flight), LDS tree reduce, thread 0 writes scale/shift.
__global__ __launch_bounds__(256) void bn_reduce(const float* __restrict__ part,
                                                 const float* __restrict__ gamma,
                                                 const float* __restrict__ beta,
                                                 float* __restrict__ ss, float invN) {
    const int f = blockIdx.x;      // feature 0..255
    const int t = threadIdx.x;     // partial-block 0..255
    __shared__ float rs[256], rq[256];
    rs[t] = part[t * 512 + f];
    rq[t] = part[t * 512 + 256 + f];
    __syncthreads();
#pragma unroll
    for (int off = 128; off > 0; off >>= 1) {
        if (t < off) { rs[t] += rs[t + off]; rq[t] += rq[t + off]; }
        __syncthreads();
    }
    if (t == 0) {
        float mu  = rs[0] * invN;
        float var = fmaf(-mu, mu, rq[0] * invN);
        float sc  = gamma[f] * rsqrtf(var + 1e-5f);
        ss[f]       = sc;
        ss[256 + f] = fmaf(-sc, mu, beta[f]);
    }
}

// bn + relu: read abuf (h2, bf16), write hbuf (post-BN h, bf16)
__global__ __launch_bounds__(256) void bn_apply(const unsigned short* __restrict__ a,
                                                const float* __restrict__ ss,
                                                unsigned short* __restrict__ h, int n8) {
    int i = blockIdx.x * 256 + threadIdx.x;
    if (i >= n8) return;
    int j = i & 31;                       // 256 feats = 32 bf16x8 groups
    const f32x4* ssv = reinterpret_cast<const f32x4*>(ss);
    f32x4 sc0 = ssv[2 * j],      sc1 = ssv[2 * j + 1];
    f32x4 sh0 = ssv[64 + 2 * j], sh1 = ssv[64 + 2 * j + 1];
    bf16x8 v = reinterpret_cast<const bf16x8*>(a)[i];
    bf16x8 r;
#pragma unroll
    for (int c = 0; c < 4; ++c)
        r[c] = (short)f2bf(fmaxf(fmaf(bf2f((unsigned short)v[c]), sc0[c], sh0[c]), 0.0f));
#pragma unroll
    for (int c = 0; c < 4; ++c)
        r[4 + c] = (short)f2bf(fmaxf(fmaf(bf2f((unsigned short)v[4 + c]), sc1[c], sh1[c]), 0.0f));
    reinterpret_cast<bf16x8*>(h)[i] = r;
}

// ------------------------------------------------------------- mean pool
// Vectorized like bn_stats: (tf, rg) layout, bf16x8 loads, LDS reduce.
__global__ __launch_bounds__(256) void pool_mean(const unsigned short* __restrict__ h,
                                                 const int* __restrict__ batch,
                                                 float* __restrict__ pooled, int nRows) {
    const int g  = blockIdx.x;
    const int t  = threadIdx.x;
    const int tf = t & 31;
    const int rg = t >> 5;
    int lo = 0, hi = nRows;
    while (lo < hi) { int mid = (lo + hi) >> 1; if (batch[mid] < g) lo = mid + 1; else hi = mid; }
    int start = lo;
    hi = nRows;
    while (lo < hi) { int mid = (lo + hi) >> 1; if (batch[mid] < g + 1) lo = mid + 1; else hi = mid; }
    int end = lo;
    float s[8];
#pragma unroll
    for (int c = 0; c < 8; ++c) s[c] = 0.f;
    for (int r = start + rg; r < end; r += 8) {
        bf16x8 hv = reinterpret_cast<const bf16x8*>(h + (size_t)r * 256)[tf];
#pragma unroll
        for (int c = 0; c < 8; ++c) s[c] += bf2f((unsigned short)hv[c]);
    }
    __shared__ float red[8][256];
#pragma unroll
    for (int c = 0; c < 8; ++c) red[rg][tf * 8 + c] = s[c];
    __syncthreads();
    float ts = 0.f;
#pragma unroll
    for (int q = 0; q < 8; ++q) ts += red[q][t];
    pooled[g * 256 + t] = ts / (float)max(end - start, 1);
}

// ----------------------------------------------------- small head GEMMs
template<int K1, int K2, int N, int ACT>
__global__ void head_gemm(const float* __restrict__ A1, const float* __restrict__ A2,
                          const float* __restrict__ W, const float* __restrict__ bias,
                          float* __restrict__ out) {
    __shared__ float srow[K1 + K2];
    const int g = blockIdx.x, t = threadIdx.x;
    for (int i = t; i < K1; i += blockDim.x) srow[i] = A1[g * K1 + i];
    if (K2 > 0)
        for (int i = t; i < K2; i += blockDim.x) srow[K1 + i] = A2[g * K2 + i];
    __syncthreads();
    if (t < N) {
        float acc = bias[t];
        for (int k = 0; k < K1 + K2; ++k) acc = fmaf(srow[k], W[k * N + t], acc);
        if (ACT == 1) acc = fmaxf(acc, 0.0f);
        if (ACT == 2) acc = tanhf(acc) * 0.5f + 0.5f;
        out[g * N + t] = acc;
    }
}

// --------------------------------------------- weight transpose to bf16
struct WTParams {
    const float* src[6];
    unsigned short* dst[6];
    int K[6];
};
__global__ void transpose_w(WTParams p) {
    const int w = blockIdx.x;
    const int K = p.K[w];
    const float* s = p.src[w];
    unsigned short* d = p.dst[w];
    const int total = K * 256;
    for (int idx = threadIdx.x; idx < total; idx += blockDim.x) {
        int n = idx / K, k = idx - n * K;
        d[idx] = f2bf(s[k * 256 + n]);
    }
}

// ---------------------------------------------------------------- launch
extern "C" void kernel_launch(void* const* d_in, const int* in_sizes, int n_in,
                              void* d_out, int out_size, void* d_ws, size_t ws_size,
                              hipStream_t stream) {
    const float* x       = (const float*)d_in[0];
    const int*   ei      = (const int*)d_in[1];
    const int*   batch   = (const int*)d_in[2];
    const float* lattice = (const float*)d_in[3];
    const float* w0a = (const float*)d_in[4],  *b0a = (const float*)d_in[5];
    const float* w0b = (const float*)d_in[6],  *b0b = (const float*)d_in[7];
    const float* g0  = (const float*)d_in[8],  *be0 = (const float*)d_in[9];
    const float* w1a = (const float*)d_in[10], *b1a = (const float*)d_in[11];
    const float* w1b = (const float*)d_in[12], *b1b = (const float*)d_in[13];
    const float* g1  = (const float*)d_in[14], *be1 = (const float*)d_in[15];
    const float* w2a = (const float*)d_in[16], *b2a = (const float*)d_in[17];
    const float* w2b = (const float*)d_in[18], *b2b = (const float*)d_in[19];
    const float* g2  = (const float*)d_in[20], *be2 = (const float*)d_in[21];
    const float* lw1 = (const float*)d_in[22], *lb1 = (const float*)d_in[23];
    const float* lw2 = (const float*)d_in[24], *lb2 = (const float*)d_in[25];
    const float* fc1w= (const float*)d_in[26], *fc1b= (const float*)d_in[27];
    const float* fc2w= (const float*)d_in[28], *fc2b= (const float*)d_in[29];

    const int* srcI = ei;
    const int* dstI = ei + NE;

    char* base = (char*)d_ws;
    size_t used = 0;
    auto alloc = [&](size_t bytes) -> char* {
        char* p = base + used;
        used += (bytes + 255) & ~(size_t)255;
        return p;
    };
    unsigned short* hbuf = (unsigned short*)alloc((size_t)NN * 256 * 2); // 25.6 MB
    unsigned short* abuf = (unsigned short*)alloc((size_t)NN * 256 * 2); // 25.6 MB
    int*            list = (int*)alloc((size_t)NN * CAP * 4);            // 12.8 MB
    int*            deg  = (int*)alloc((size_t)NN * 4);                  //  0.2 MB
    unsigned short* w0aT = (unsigned short*)alloc(256 * 128 * 2);
    unsigned short* w0bT = (unsigned short*)alloc(256 * 256 * 2);
    unsigned short* w1aT = (unsigned short*)alloc(256 * 256 * 2);
    unsigned short* w1bT = (unsigned short*)alloc(256 * 256 * 2);
    unsigned short* w2aT = (unsigned short*)alloc(256 * 256 * 2);
    unsigned short* w2bT = (unsigned short*)alloc(256 * 256 * 2);
    float* part   = (float*)alloc(256 * 512 * 4);
    float* ss     = (float*)alloc(512 * 4);
    float* pooled = (float*)alloc(128 * 256 * 4);
    float* latb   = (float*)alloc(128 * 256 * 4);
    float* latb2  = (float*)alloc(128 * 256 * 4);
    float* c1     = (float*)alloc(128 * 256 * 4);

    // Workspace guard (deterministic; graph-capture safe).
    if (used > ws_size) return;

    // weight transposes (bf16, [N,K])
    WTParams tp;
    tp.src[0] = w0a; tp.dst[0] = w0aT; tp.K[0] = 128;
    tp.src[1] = w0b; tp.dst[1] = w0bT; tp.K[1] = 256;
    tp.src[2] = w1a; tp.dst[2] = w1aT; tp.K[2] = 256;
    tp.src[3] = w1b; tp.dst[3] = w1bT; tp.K[3] = 256;
    tp.src[4] = w2a; tp.dst[4] = w2aT; tp.K[4] = 256;
    tp.src[5] = w2b; tp.dst[5] = w2bT; tp.K[5] = 256;
    transpose_w<<<6, 256, 0, stream>>>(tp);

    // adjacency (built once; reused by all 3 layers)
    zero_deg<<<(NN + 255) / 256, 256, 0, stream>>>(deg);
    fill_edges<<<(NE + 255) / 256, 256, 0, stream>>>(srcI, dstI, deg, list);

    const int gemmBlocks = (NN + 63) / 64;   // 782
    const int aggBlocks  = (NN + 3) / 4;     // 12500
    const int n8         = NN * 32;          // bf16x8 chunks of [NN][256]

    // ---- layer 0 (D_in = 128)
    init0<<<(NN * 32 + 255) / 256, 256, 0, stream>>>(x, hbuf);
    aggregate<128><<<aggBlocks, 256, 0, stream>>>(deg, list, hbuf, abuf);
    node_gemm<128, true ><<<gemmBlocks, 256, 0, stream>>>(abuf, w0aT, b0a, NN);
    node_gemm<256, false><<<gemmBlocks, 256, 0, stream>>>(abuf, w0bT, b0b, NN);
    bn_stats<<<256, 256, 0, stream>>>(abuf, part, NN);
    bn_reduce<<<256, 256, 0, stream>>>(part, g0, be0, ss, 1.0f / NN);
    bn_apply<<<(n8 + 255) / 256, 256, 0, stream>>>(abuf, ss, hbuf, n8);

    // ---- layer 1
    aggregate<256><<<aggBlocks, 256, 0, stream>>>(deg, list, hbuf, abuf);
    node_gemm<256, true ><<<gemmBlocks, 256, 0, stream>>>(abuf, w1aT, b1a, NN);
    node_gemm<256, false><<<gemmBlocks, 256, 0, stream>>>(abuf, w1bT, b1b, NN);
    bn_stats<<<256, 256, 0, stream>>>(abuf, part, NN);
    bn_reduce<<<256, 256, 0, stream>>>(part, g1, be1, ss, 1.0f / NN);
    bn_apply<<<(n8 + 255) / 256, 256, 0, stream>>>(abuf, ss, hbuf, n8);

    // ---- layer 2
    aggregate<256><<<aggBlocks, 256, 0, stream>>>(deg, list, hbuf, abuf);
    node_gemm<256, true ><<<gemmBlocks, 256, 0, stream>>>(abuf, w2aT, b2a, NN);
    node_gemm<256, false><<<gemmBlocks, 256, 0, stream>>>(abuf, w2bT, b2b, NN);
    bn_stats<<<256, 256, 0, stream>>>(abuf, part, NN);
    bn_reduce<<<256, 256, 0, stream>>>(part, g2, be2, ss, 1.0f / NN);
    bn_apply<<<(n8 + 255) / 256, 256, 0, stream>>>(abuf, ss, hbuf, n8);

    // ---- pooling + head
    pool_mean<<<NG, 256, 0, stream>>>(hbuf, batch, pooled, NN);
    head_gemm<9,   0,   256, 1><<<NG, 256, 0, stream>>>(lattice, nullptr, lw1, lb1, latb);
    head_gemm<256, 0,   256, 1><<<NG, 256, 0, stream>>>(latb, nullptr, lw2, lb2, latb2);
    head_gemm<256, 256, 256, 1><<<NG, 256, 0, stream>>>(pooled, latb2, fc1w, fc1b, c1);
    head_gemm<256, 0,   32,  2><<<NG, 64, 0, stream>>>(c1, nullptr, fc2w, fc2b, (float*)d_out);
}

// Round 15
// 651.203 us; speedup vs baseline: 1.9772x; 1.0733x over previous
//
#include <hip/hip_runtime.h>
#include <hip/hip_bf16.h>

#define NN 50000
#define NE 800000
#define NG 128
#define CAP 64

typedef __attribute__((ext_vector_type(4))) float f32x4;
typedef __attribute__((ext_vector_type(8))) short bf16x8;
typedef __attribute__((ext_vector_type(4))) short short4v;
typedef __attribute__((ext_vector_type(2))) short short2v;

__device__ __forceinline__ float bf2f(unsigned short u) {
    union { unsigned int i; float f; } c; c.i = ((unsigned int)u) << 16; return c.f;
}
__device__ __forceinline__ unsigned short f2bf(float f) {
    __hip_bfloat16 b = __float2bfloat16(f);
    return *reinterpret_cast<unsigned short*>(&b);
}

template<int V> struct VecPick;
template<> struct VecPick<4> { using T = short4v; };
template<> struct VecPick<2> { using T = short2v; };

// --------------------------------------------------------------- zero deg
__global__ __launch_bounds__(256) void zero_deg(int* __restrict__ deg) {
    int i = blockIdx.x * 256 + threadIdx.x;
    if (i < NN) deg[i] = 0;
}

// ------------------------------------------- build padded adjacency lists
__global__ __launch_bounds__(256) void fill_edges(const int* __restrict__ src,
                                                  const int* __restrict__ dst,
                                                  int* __restrict__ deg,
                                                  int* __restrict__ list) {
    int e = blockIdx.x * 256 + threadIdx.x;
    if (e >= NE) return;
    int d = dst[e], s = src[e];
    if ((unsigned)d >= NN || (unsigned)s >= NN) return;   // defensive
    int slot = atomicAdd(&deg[d], 1);
    if (slot < CAP) list[d * CAP + slot] = s;
}

// ------------------------------------------------- layer-0 feature init
__global__ __launch_bounds__(256) void init0(const float* __restrict__ x,
                                             unsigned short* __restrict__ h) {
    int i = blockIdx.x * 256 + threadIdx.x;     // over NN*32 f32x4 chunks
    if (i >= NN * 32) return;
    int node = i >> 5, c4 = i & 31;
    f32x4 v = reinterpret_cast<const f32x4*>(x)[i];
    short4v b;
#pragma unroll
    for (int c = 0; c < 4; ++c) b[c] = (short)f2bf(v[c]);
    reinterpret_cast<short4v*>(h)[node * 64 + c4] = b;
}

// ---------------------------------------------- gather-based aggregation
// abuf[i] = h[i] + sum_{s in N(i)} h[s]. One wave per node.
// Unroll x8: 8 independent row loads in flight (r13: x4 gave 46% HBM peak).
template<int D>
__global__ __launch_bounds__(256) void aggregate(const int* __restrict__ deg,
                                                 const int* __restrict__ list,
                                                 const unsigned short* __restrict__ h,
                                                 unsigned short* __restrict__ abuf) {
    constexpr int V = D / 64;                  // 2 or 4
    using VT = typename VecPick<V>::T;
    int node = blockIdx.x * 4 + (threadIdx.x >> 6);
    if (node >= NN) return;
    const int l = threadIdx.x & 63;
    int d = deg[node]; d = d < CAP ? d : CAP;
    const int* li = list + node * CAP;
    float acc[V];
    {
        VT t = *reinterpret_cast<const VT*>(h + (size_t)node * 256 + l * V);
#pragma unroll
        for (int c = 0; c < V; ++c) acc[c] = bf2f((unsigned short)t[c]);
    }
    int e = 0;
    for (; e + 8 <= d; e += 8) {
        VT hv[8];
#pragma unroll
        for (int q = 0; q < 8; ++q) {
            int s = li[e + q];
            hv[q] = *reinterpret_cast<const VT*>(h + (size_t)s * 256 + l * V);
        }
#pragma unroll
        for (int q = 0; q < 8; ++q)
#pragma unroll
            for (int c = 0; c < V; ++c) acc[c] += bf2f((unsigned short)hv[q][c]);
    }
    for (; e + 4 <= d; e += 4) {
        VT hv[4];
#pragma unroll
        for (int q = 0; q < 4; ++q) {
            int s = li[e + q];
            hv[q] = *reinterpret_cast<const VT*>(h + (size_t)s * 256 + l * V);
        }
#pragma unroll
        for (int q = 0; q < 4; ++q)
#pragma unroll
            for (int c = 0; c < V; ++c) acc[c] += bf2f((unsigned short)hv[q][c]);
    }
    for (; e < d; ++e) {
        int s = li[e];
        VT hv = *reinterpret_cast<const VT*>(h + (size_t)s * 256 + l * V);
#pragma unroll
        for (int c = 0; c < V; ++c) acc[c] += bf2f((unsigned short)hv[c]);
    }
    VT t;
#pragma unroll
    for (int c = 0; c < V; ++c) t[c] = (short)f2bf(acc[c]);
    *reinterpret_cast<VT*>(abuf + (size_t)node * 256 + l * V) = t;
}

// ------------------------------------- fused per-layer MLP (bf16 MFMA)
// AC[M,256] bf16 IN-PLACE:  AC = relu(AC[:,0..K1) @ W1 + b1) @ W2 + b2
// Phase 1: GEMM1 (A global) -> relu -> ctile (LDS).  Phase 2: GEMM2
// (A from LDS, W2 from L2) -> ctile -> coalesced store. Kills the 25.6MB
// h1 global round-trip per layer (r13: each node_gemm ~55us, 6 total).
// ctile row stride 264 shorts: phase-2 ds_read_b128 start-bank = 4*lane
// mod 32 -> 2-way alias worst case = free [m136].
template<int K1>
__global__ __launch_bounds__(256) void node_mlp(unsigned short* AC,
                                                const unsigned short* __restrict__ W1T,
                                                const float* __restrict__ b1,
                                                const unsigned short* __restrict__ W2T,
                                                const float* __restrict__ b2,
                                                int M) {
    const int lane = threadIdx.x & 63;
    const int wid  = threadIdx.x >> 6;
    const int row0 = blockIdx.x * 64;
    const int col0 = wid * 64;
    const int r16  = lane & 15;
    const int kg   = lane >> 4;          // k-group 0..3

    __shared__ unsigned short ctile[64][264];

    f32x4 acc[4][4];
#pragma unroll
    for (int m = 0; m < 4; ++m)
#pragma unroll
        for (int n = 0; n < 4; ++n) acc[m][n] = (f32x4)0.0f;

    // ---------------- phase 1: h1 = relu(A @ W1 + b1), A from global
#pragma unroll
    for (int ks = 0; ks < K1 / 32; ++ks) {
        const int kb = ks * 32 + kg * 8;
        bf16x8 afr[4];
#pragma unroll
        for (int m = 0; m < 4; ++m) {
            int row = row0 + m * 16 + r16;
            row = row < M ? row : M - 1;
            afr[m] = *reinterpret_cast<const bf16x8*>(AC + (size_t)row * 256 + kb);
        }
#pragma unroll
        for (int n = 0; n < 4; ++n) {
            const int col = col0 + n * 16 + r16;
            bf16x8 bfr = *reinterpret_cast<const bf16x8*>(W1T + (size_t)col * K1 + kb);
#pragma unroll
            for (int m = 0; m < 4; ++m)
                acc[m][n] = __builtin_amdgcn_mfma_f32_16x16x32_bf16(afr[m], bfr, acc[m][n], 0, 0, 0);
        }
    }
    // epilogue1 -> ctile (relu). wave owns cols col0..col0+63: race-free.
#pragma unroll
    for (int n = 0; n < 4; ++n) {
        const int col = col0 + n * 16 + r16;
        const float bv = b1[col];
#pragma unroll
        for (int m = 0; m < 4; ++m) {
#pragma unroll
            for (int j = 0; j < 4; ++j) {
                int lrow = m * 16 + kg * 4 + j;
                ctile[lrow][col] = f2bf(fmaxf(acc[m][n][j] + bv, 0.0f));
            }
        }
    }
    __syncthreads();   // h1 tile complete (and all phase-1 A reads done)

    // ---------------- phase 2: h2 = h1 @ W2 + b2, A from LDS
#pragma unroll
    for (int m = 0; m < 4; ++m)
#pragma unroll
        for (int n = 0; n < 4; ++n) acc[m][n] = (f32x4)0.0f;
#pragma unroll
    for (int ks = 0; ks < 8; ++ks) {
        const int kb = ks * 32 + kg * 8;
        bf16x8 afr[4];
#pragma unroll
        for (int m = 0; m < 4; ++m)
            afr[m] = *reinterpret_cast<const bf16x8*>(&ctile[m * 16 + r16][kb]);
#pragma unroll
        for (int n = 0; n < 4; ++n) {
            const int col = col0 + n * 16 + r16;
            bf16x8 bfr = *reinterpret_cast<const bf16x8*>(W2T + (size_t)col * 256 + kb);
#pragma unroll
            for (int m = 0; m < 4; ++m)
                acc[m][n] = __builtin_amdgcn_mfma_f32_16x16x32_bf16(afr[m], bfr, acc[m][n], 0, 0, 0);
        }
    }
    __syncthreads();   // all phase-2 LDS reads done before ctile overwrite
    // epilogue2 -> ctile (no relu)
#pragma unroll
    for (int n = 0; n < 4; ++n) {
        const int col = col0 + n * 16 + r16;
        const float bv = b2[col];
#pragma unroll
        for (int m = 0; m < 4; ++m) {
#pragma unroll
            for (int j = 0; j < 4; ++j) {
                int lrow = m * 16 + kg * 4 + j;
                ctile[lrow][col] = f2bf(acc[m][n][j] + bv);
            }
        }
    }
    __syncthreads();
    // coalesced store: 64 rows x 32 chunks of 8 shorts (16B/lane)
    const int t = threadIdx.x;
#pragma unroll
    for (int c = t; c < 64 * 32; c += 256) {
        int lrow = c >> 5, cc = (c & 31) * 8;
        int grow = row0 + lrow;
        if (grow < M) {
            bf16x8 v = *reinterpret_cast<const bf16x8*>(&ctile[lrow][cc]);
            *reinterpret_cast<bf16x8*>(AC + (size_t)grow * 256 + cc) = v;
        }
    }
}

// ------------------------------------------------------------- batchnorm
#define BN_ROWS_PER_BLOCK 196   // 256 * 196 >= 50000
__global__ __launch_bounds__(256) void bn_stats(const unsigned short* __restrict__ h,
                                                float* __restrict__ part, int nRows) {
    const int t  = threadIdx.x;
    const int tf = t & 31;       // feature chunk (8 feats)
    const int rg = t >> 5;       // row group 0..7
    const int r0 = blockIdx.x * BN_ROWS_PER_BLOCK;
    const int r1 = min(r0 + BN_ROWS_PER_BLOCK, nRows);
    float s[8], s2[8];
#pragma unroll
    for (int c = 0; c < 8; ++c) { s[c] = 0.f; s2[c] = 0.f; }
    for (int r = r0 + rg; r < r1; r += 8) {
        bf16x8 hv = reinterpret_cast<const bf16x8*>(h + (size_t)r * 256)[tf];
#pragma unroll
        for (int c = 0; c < 8; ++c) {
            float v = bf2f((unsigned short)hv[c]);
            s[c] += v;
            s2[c] = fmaf(v, v, s2[c]);
        }
    }
    __shared__ float redS[8][256];
    __shared__ float redQ[8][256];
#pragma unroll
    for (int c = 0; c < 8; ++c) {
        redS[rg][tf * 8 + c] = s[c];
        redQ[rg][tf * 8 + c] = s2[c];
    }
    __syncthreads();
    float ts = 0.f, tq = 0.f;
#pragma unroll
    for (int g = 0; g < 8; ++g) { ts += redS[g][t]; tq += redQ[g][t]; }
    part[blockIdx.x * 512 + t]       = ts;
    part[blockIdx.x * 512 + 256 + t] = tq;
}

// one block per feature; thread t loads bn_stats block t's partial.
__global__ __launch_bounds__(256) void bn_reduce(const float* __restrict__ part,
                                                 const float* __restrict__ gamma,
                                                 const float* __restrict__ beta,
                                                 float* __restrict__ ss, float invN) {
    const int f = blockIdx.x;      // feature 0..255
    const int t = threadIdx.x;     // partial-block 0..255
    __shared__ float rs[256], rq[256];
    rs[t] = part[t * 512 + f];
    rq[t] = part[t * 512 + 256 + f];
    __syncthreads();
#pragma unroll
    for (int off = 128; off > 0; off >>= 1) {
        if (t < off) { rs[t] += rs[t + off]; rq[t] += rq[t + off]; }
        __syncthreads();
    }
    if (t == 0) {
        float mu  = rs[0] * invN;
        float var = fmaf(-mu, mu, rq[0] * invN);
        float sc  = gamma[f] * rsqrtf(var + 1e-5f);
        ss[f]       = sc;
        ss[256 + f] = fmaf(-sc, mu, beta[f]);
    }
}

// bn + relu: read abuf (h2, bf16), write hbuf (post-BN h, bf16)
__global__ __launch_bounds__(256) void bn_apply(const unsigned short* __restrict__ a,
                                                const float* __restrict__ ss,
                                                unsigned short* __restrict__ h, int n8) {
    int i = blockIdx.x * 256 + threadIdx.x;
    if (i >= n8) return;
    int j = i & 31;                       // 256 feats = 32 bf16x8 groups
    const f32x4* ssv = reinterpret_cast<const f32x4*>(ss);
    f32x4 sc0 = ssv[2 * j],      sc1 = ssv[2 * j + 1];
    f32x4 sh0 = ssv[64 + 2 * j], sh1 = ssv[64 + 2 * j + 1];
    bf16x8 v = reinterpret_cast<const bf16x8*>(a)[i];
    bf16x8 r;
#pragma unroll
    for (int c = 0; c < 4; ++c)
        r[c] = (short)f2bf(fmaxf(fmaf(bf2f((unsigned short)v[c]), sc0[c], sh0[c]), 0.0f));
#pragma unroll
    for (int c = 0; c < 4; ++c)
        r[4 + c] = (short)f2bf(fmaxf(fmaf(bf2f((unsigned short)v[4 + c]), sc1[c], sh1[c]), 0.0f));
    reinterpret_cast<bf16x8*>(h)[i] = r;
}

// ------------------------------------------------------------- mean pool
__global__ __launch_bounds__(256) void pool_mean(const unsigned short* __restrict__ h,
                                                 const int* __restrict__ batch,
                                                 float* __restrict__ pooled, int nRows) {
    const int g  = blockIdx.x;
    const int t  = threadIdx.x;
    const int tf = t & 31;
    const int rg = t >> 5;
    int lo = 0, hi = nRows;
    while (lo < hi) { int mid = (lo + hi) >> 1; if (batch[mid] < g) lo = mid + 1; else hi = mid; }
    int start = lo;
    hi = nRows;
    while (lo < hi) { int mid = (lo + hi) >> 1; if (batch[mid] < g + 1) lo = mid + 1; else hi = mid; }
    int end = lo;
    float s[8];
#pragma unroll
    for (int c = 0; c < 8; ++c) s[c] = 0.f;
    for (int r = start + rg; r < end; r += 8) {
        bf16x8 hv = reinterpret_cast<const bf16x8*>(h + (size_t)r * 256)[tf];
#pragma unroll
        for (int c = 0; c < 8; ++c) s[c] += bf2f((unsigned short)hv[c]);
    }
    __shared__ float red[8][256];
#pragma unroll
    for (int c = 0; c < 8; ++c) red[rg][tf * 8 + c] = s[c];
    __syncthreads();
    float ts = 0.f;
#pragma unroll
    for (int q = 0; q < 8; ++q) ts += red[q][t];
    pooled[g * 256 + t] = ts / (float)max(end - start, 1);
}

// ----------------------------------------------------- small head GEMMs
template<int K1, int K2, int N, int ACT>
__global__ void head_gemm(const float* __restrict__ A1, const float* __restrict__ A2,
                          const float* __restrict__ W, const float* __restrict__ bias,
                          float* __restrict__ out) {
    __shared__ float srow[K1 + K2];
    const int g = blockIdx.x, t = threadIdx.x;
    for (int i = t; i < K1; i += blockDim.x) srow[i] = A1[g * K1 + i];
    if (K2 > 0)
        for (int i = t; i < K2; i += blockDim.x) srow[K1 + i] = A2[g * K2 + i];
    __syncthreads();
    if (t < N) {
        float acc = bias[t];
        for (int k = 0; k < K1 + K2; ++k) acc = fmaf(srow[k], W[k * N + t], acc);
        if (ACT == 1) acc = fmaxf(acc, 0.0f);
        if (ACT == 2) acc = tanhf(acc) * 0.5f + 0.5f;
        out[g * N + t] = acc;
    }
}

// --------------------------------------------- weight transpose to bf16
struct WTParams {
    const float* src[6];
    unsigned short* dst[6];
    int K[6];
};
__global__ void transpose_w(WTParams p) {
    const int w = blockIdx.x;
    const int K = p.K[w];
    const float* s = p.src[w];
    unsigned short* d = p.dst[w];
    const int total = K * 256;
    for (int idx = threadIdx.x; idx < total; idx += blockDim.x) {
        int n = idx / K, k = idx - n * K;
        d[idx] = f2bf(s[k * 256 + n]);
    }
}

// ---------------------------------------------------------------- launch
extern "C" void kernel_launch(void* const* d_in, const int* in_sizes, int n_in,
                              void* d_out, int out_size, void* d_ws, size_t ws_size,
                              hipStream_t stream) {
    const float* x       = (const float*)d_in[0];
    const int*   ei      = (const int*)d_in[1];
    const int*   batch   = (const int*)d_in[2];
    const float* lattice = (const float*)d_in[3];
    const float* w0a = (const float*)d_in[4],  *b0a = (const float*)d_in[5];
    const float* w0b = (const float*)d_in[6],  *b0b = (const float*)d_in[7];
    const float* g0  = (const float*)d_in[8],  *be0 = (const float*)d_in[9];
    const float* w1a = (const float*)d_in[10], *b1a = (const float*)d_in[11];
    const float* w1b = (const float*)d_in[12], *b1b = (const float*)d_in[13];
    const float* g1  = (const float*)d_in[14], *be1 = (const float*)d_in[15];
    const float* w2a = (const float*)d_in[16], *b2a = (const float*)d_in[17];
    const float* w2b = (const float*)d_in[18], *b2b = (const float*)d_in[19];
    const float* g2  = (const float*)d_in[20], *be2 = (const float*)d_in[21];
    const float* lw1 = (const float*)d_in[22], *lb1 = (const float*)d_in[23];
    const float* lw2 = (const float*)d_in[24], *lb2 = (const float*)d_in[25];
    const float* fc1w= (const float*)d_in[26], *fc1b= (const float*)d_in[27];
    const float* fc2w= (const float*)d_in[28], *fc2b= (const float*)d_in[29];

    const int* srcI = ei;
    const int* dstI = ei + NE;

    char* base = (char*)d_ws;
    size_t used = 0;
    auto alloc = [&](size_t bytes) -> char* {
        char* p = base + used;
        used += (bytes + 255) & ~(size_t)255;
        return p;
    };
    unsigned short* hbuf = (unsigned short*)alloc((size_t)NN * 256 * 2); // 25.6 MB
    unsigned short* abuf = (unsigned short*)alloc((size_t)NN * 256 * 2); // 25.6 MB
    int*            list = (int*)alloc((size_t)NN * CAP * 4);            // 12.8 MB
    int*            deg  = (int*)alloc((size_t)NN * 4);                  //  0.2 MB
    unsigned short* w0aT = (unsigned short*)alloc(256 * 128 * 2);
    unsigned short* w0bT = (unsigned short*)alloc(256 * 256 * 2);
    unsigned short* w1aT = (unsigned short*)alloc(256 * 256 * 2);
    unsigned short* w1bT = (unsigned short*)alloc(256 * 256 * 2);
    unsigned short* w2aT = (unsigned short*)alloc(256 * 256 * 2);
    unsigned short* w2bT = (unsigned short*)alloc(256 * 256 * 2);
    float* part   = (float*)alloc(256 * 512 * 4);
    float* ss     = (float*)alloc(512 * 4);
    float* pooled = (float*)alloc(128 * 256 * 4);
    float* latb   = (float*)alloc(128 * 256 * 4);
    float* latb2  = (float*)alloc(128 * 256 * 4);
    float* c1     = (float*)alloc(128 * 256 * 4);

    // Workspace guard (deterministic; graph-capture safe).
    if (used > ws_size) return;

    // weight transposes (bf16, [N,K])
    WTParams tp;
    tp.src[0] = w0a; tp.dst[0] = w0aT; tp.K[0] = 128;
    tp.src[1] = w0b; tp.dst[1] = w0bT; tp.K[1] = 256;
    tp.src[2] = w1a; tp.dst[2] = w1aT; tp.K[2] = 256;
    tp.src[3] = w1b; tp.dst[3] = w1bT; tp.K[3] = 256;
    tp.src[4] = w2a; tp.dst[4] = w2aT; tp.K[4] = 256;
    tp.src[5] = w2b; tp.dst[5] = w2bT; tp.K[5] = 256;
    transpose_w<<<6, 256, 0, stream>>>(tp);

    // adjacency (built once; reused by all 3 layers)
    zero_deg<<<(NN + 255) / 256, 256, 0, stream>>>(deg);
    fill_edges<<<(NE + 255) / 256, 256, 0, stream>>>(srcI, dstI, deg, list);

    const int gemmBlocks = (NN + 63) / 64;   // 782
    const int aggBlocks  = (NN + 3) / 4;     // 12500
    const int n8         = NN * 32;          // bf16x8 chunks of [NN][256]

    // ---- layer 0 (D_in = 128)
    init0<<<(NN * 32 + 255) / 256, 256, 0, stream>>>(x, hbuf);
    aggregate<128><<<aggBlocks, 256, 0, stream>>>(deg, list, hbuf, abuf);
    node_mlp<128><<<gemmBlocks, 256, 0, stream>>>(abuf, w0aT, b0a, w0bT, b0b, NN);
    bn_stats<<<256, 256, 0, stream>>>(abuf, part, NN);
    bn_reduce<<<256, 256, 0, stream>>>(part, g0, be0, ss, 1.0f / NN);
    bn_apply<<<(n8 + 255) / 256, 256, 0, stream>>>(abuf, ss, hbuf, n8);

    // ---- layer 1
    aggregate<256><<<aggBlocks, 256, 0, stream>>>(deg, list, hbuf, abuf);
    node_mlp<256><<<gemmBlocks, 256, 0, stream>>>(abuf, w1aT, b1a, w1bT, b1b, NN);
    bn_stats<<<256, 256, 0, stream>>>(abuf, part, NN);
    bn_reduce<<<256, 256, 0, stream>>>(part, g1, be1, ss, 1.0f / NN);
    bn_apply<<<(n8 + 255) / 256, 256, 0, stream>>>(abuf, ss, hbuf, n8);

    // ---- layer 2
    aggregate<256><<<aggBlocks, 256, 0, stream>>>(deg, list, hbuf, abuf);
    node_mlp<256><<<gemmBlocks, 256, 0, stream>>>(abuf, w2aT, b2a, w2bT, b2b, NN);
    bn_stats<<<256, 256, 0, stream>>>(abuf, part, NN);
    bn_reduce<<<256, 256, 0, stream>>>(part, g2, be2, ss, 1.0f / NN);
    bn_apply<<<(n8 + 255) / 256, 256, 0, stream>>>(abuf, ss, hbuf, n8);

    // ---- pooling + head
    pool_mean<<<NG, 256, 0, stream>>>(hbuf, batch, pooled, NN);
    head_gemm<9,   0,   256, 1><<<NG, 256, 0, stream>>>(lattice, nullptr, lw1, lb1, latb);
    head_gemm<256, 0,   256, 1><<<NG, 256, 0, stream>>>(latb, nullptr, lw2, lb2, latb2);
    head_gemm<256, 256, 256, 1><<<NG, 256, 0, stream>>>(pooled, latb2, fc1w, fc1b, c1);
    head_gemm<256, 0,   32,  2><<<NG, 64, 0, stream>>>(c1, nullptr, fc2w, fc2b, (float*)d_out);
}